// Round 2
// baseline (1032.690 us; speedup 1.0000x reference)
//
#include <hip/hip_runtime.h>
#include <hip/hip_bf16.h>
#include <math.h>

// Problem constants (MambaEncoder)
#define Bz     8
#define Lz     8192
#define DM     128      // d_model
#define DI     256      // d_inner
#define DS     16       // d_state
#define DTR    8        // dt_rank
#define NDBL   40       // DTR + 2*DS
#define DEPTHN 4
#define BLz    (Bz*Lz)  // 65536 tokens
#define CHT    64       // scan chunk length == M-tile
#define NCH    (Lz/CHT) // 128 chunks per sequence
#define PADI   264      // bf16 tile row stride
#define PADD   44       // f32 Db row stride

typedef unsigned short bf16_t;
typedef __attribute__((ext_vector_type(8))) __bf16 bf8;
typedef __attribute__((ext_vector_type(4))) float f4;
typedef __attribute__((ext_vector_type(8))) unsigned short us8;

__device__ __forceinline__ float bf2f(bf16_t u) {
    return __uint_as_float(((unsigned)u) << 16);
}
__device__ __forceinline__ bf16_t f2bf(float f) {
    unsigned u = __float_as_uint(f);
    u = u + 0x7FFFu + ((u >> 16) & 1u);   // round-to-nearest-even
    return (bf16_t)(u >> 16);
}
__device__ __forceinline__ float fast_rcp(float x) {
    return __builtin_amdgcn_rcpf(x);
}

// dA power tree: dA[s] = e1^(s+1), depth 4.
__device__ __forceinline__ void pow_tree(float e1, float dA[DS]) {
    float e2 = e1 * e1, e3 = e2 * e1, e4 = e2 * e2;
    float e8 = e4 * e4;
    dA[0] = e1;       dA[1] = e2;       dA[2] = e3;       dA[3] = e4;
    dA[4] = e4 * e1;  dA[5] = e4 * e2;  dA[6] = e4 * e3;  dA[7] = e8;
    dA[8] = e8 * e1;  dA[9] = e8 * e2;  dA[10] = e8 * e3; dA[11] = e8 * e4;
    dA[12] = e8 * dA[4]; dA[13] = e8 * dA[5]; dA[14] = e8 * dA[6];
    dA[15] = e8 * e8;
}

// ---------------------------------------------------------------------------
// Convert weights fp32 -> bf16 (xproj padded 40->64 rows) + zero hg.
// ---------------------------------------------------------------------------
__global__ __launch_bounds__(256) void k_wconv(const float* __restrict__ inw,
                                               const float* __restrict__ ow,
                                               const float* __restrict__ xw,
                                               bf16_t* __restrict__ inwb,
                                               bf16_t* __restrict__ owb,
                                               bf16_t* __restrict__ xwb,
                                               float* __restrict__ hg) {
    int i = blockIdx.x * 256 + threadIdx.x;
    if (i < Bz * DM) hg[i] = 0.f;
    if (i < DEPTHN * 512 * DM) inwb[i] = f2bf(inw[i]);
    if (i < DEPTHN * DM * DI)  owb[i]  = f2bf(ow[i]);
    if (i < DEPTHN * 64 * DI) {
        int layer = i >> 14, rk = i & 16383, r = rk >> 8, k = rk & 255;
        xwb[i] = (r < NDBL) ? f2bf(xw[((size_t)layer * NDBL + r) * DI + k]) : (bf16_t)0;
    }
}

// ---------------------------------------------------------------------------
__global__ __launch_bounds__(256) void k_inproj(const float* __restrict__ x,
                                                const float* __restrict__ pw,
                                                const float* __restrict__ pb,
                                                float* __restrict__ h) {
    int t = blockIdx.x * 2 + (threadIdx.x >> 7);
    int d = threadIdx.x & 127;
    int b = t >> 13, l = t & (Lz - 1);
    float acc = pb[d];
#pragma unroll
    for (int c = 0; c < 3; ++c)
        acc += x[(size_t)(b * 3 + c) * Lz + l] * pw[d * 3 + c];
    h[(size_t)t * DM + d] = acc;
}

// ---------------------------------------------------------------------------
// FUSED: LayerNorm (64 rows) -> in-proj GEMM [64x512] -> u_pre (raw) + zs
// (silu pre-applied). xn tile lives only in LDS. One block per 64 tokens.
// ---------------------------------------------------------------------------
__global__ __launch_bounds__(256) void k_lnin(const float* __restrict__ h,
                                              const float* __restrict__ lw,
                                              const float* __restrict__ lb,
                                              const bf16_t* __restrict__ inwb,
                                              bf16_t* __restrict__ u_pre,
                                              bf16_t* __restrict__ zs) {
    __shared__ bf16_t sm[64 * PADI];     // 33792 B; xs view (stride 136) first
    bf16_t* xs = sm;                      // 64 x 136 region
    int tid = threadIdx.x;
    int mBase = blockIdx.x * 64;

    // --- LayerNorm: 4 passes of 16 rows, 16 lanes/row ---
#pragma unroll
    for (int p = 0; p < 4; ++p) {
        int row = p * 16 + (tid >> 4);
        int lane = tid & 15;
        const float4* hp = (const float4*)(h + (size_t)(mBase + row) * DM + lane * 8);
        float4 v0 = hp[0], v1 = hp[1];
        float s = v0.x + v0.y + v0.z + v0.w + v1.x + v1.y + v1.z + v1.w;
        float q = v0.x*v0.x + v0.y*v0.y + v0.z*v0.z + v0.w*v0.w +
                  v1.x*v1.x + v1.y*v1.y + v1.z*v1.z + v1.w*v1.w;
#pragma unroll
        for (int off = 1; off < 16; off <<= 1) {
            s += __shfl_xor(s, off);
            q += __shfl_xor(q, off);
        }
        float mean = s * (1.f / DM);
        float var  = q * (1.f / DM) - mean * mean;
        float rstd = rsqrtf(var + 1e-5f);
        const float4* wp = (const float4*)(lw + lane * 8);
        const float4* bp = (const float4*)(lb + lane * 8);
        float4 w0 = wp[0], w1 = wp[1], b0 = bp[0], b1 = bp[1];
        ushort4 o0, o1;
        o0.x = f2bf((v0.x - mean) * rstd * w0.x + b0.x);
        o0.y = f2bf((v0.y - mean) * rstd * w0.y + b0.y);
        o0.z = f2bf((v0.z - mean) * rstd * w0.z + b0.z);
        o0.w = f2bf((v0.w - mean) * rstd * w0.w + b0.w);
        o1.x = f2bf((v1.x - mean) * rstd * w1.x + b1.x);
        o1.y = f2bf((v1.y - mean) * rstd * w1.y + b1.y);
        o1.z = f2bf((v1.z - mean) * rstd * w1.z + b1.z);
        o1.w = f2bf((v1.w - mean) * rstd * w1.w + b1.w);
        *(ushort4*)&xs[row * 136 + lane * 8]     = o0;
        *(ushort4*)&xs[row * 136 + lane * 8 + 4] = o1;
    }
    __syncthreads();

    // --- GEMM: [64 x 512] = xs[64 x 128] @ in_w^T; wave n-slice 128 ---
    int wave = tid >> 6, lane = tid & 63;
    int lr = lane & 15, lq = lane >> 4;
    int wn = wave * 128;
    f4 zf = {0.f, 0.f, 0.f, 0.f};
    f4 acc[4][8];
#pragma unroll
    for (int mi = 0; mi < 4; ++mi)
#pragma unroll
        for (int ni = 0; ni < 8; ++ni) acc[mi][ni] = zf;
    const bf16_t* Bp = inwb + (size_t)(wn + lr) * DM + lq * 8;
#pragma unroll
    for (int kk = 0; kk < DM; kk += 32) {
        bf8 af[4], bq[8];
#pragma unroll
        for (int mi = 0; mi < 4; ++mi)
            af[mi] = *(const bf8*)&xs[(mi * 16 + lr) * 136 + lq * 8 + kk];
#pragma unroll
        for (int ni = 0; ni < 8; ++ni)
            bq[ni] = *(const bf8*)(Bp + (size_t)ni * 16 * DM + kk);
#pragma unroll
        for (int mi = 0; mi < 4; ++mi)
#pragma unroll
            for (int ni = 0; ni < 8; ++ni)
                acc[mi][ni] = __builtin_amdgcn_mfma_f32_16x16x32_bf16(
                    af[mi], bq[ni], acc[mi][ni], 0, 0, 0);
    }
    __syncthreads();   // xs dead; sm reusable as 64x264 output tile

    // --- epilogue pass 1: u (cols 0..255, waves 0,1), raw bf16 ---
    if (wave < 2) {
#pragma unroll
        for (int mi = 0; mi < 4; ++mi)
#pragma unroll
            for (int ni = 0; ni < 8; ++ni)
#pragma unroll
                for (int r = 0; r < 4; ++r)
                    sm[(mi * 16 + lq * 4 + r) * PADI + wn + ni * 16 + lr] =
                        f2bf(acc[mi][ni][r]);
    }
    __syncthreads();
    for (int i = tid; i < 2048; i += 256) {
        int row = i >> 5, col = (i & 31) * 8;
        us8 v = *(const us8*)&sm[row * PADI + col];
        *(us8*)&u_pre[(size_t)(mBase + row) * DI + col] = v;
    }
    __syncthreads();
    // --- epilogue pass 2: zs = silu(z) (cols 256..511, waves 2,3) ---
    if (wave >= 2) {
#pragma unroll
        for (int mi = 0; mi < 4; ++mi)
#pragma unroll
            for (int ni = 0; ni < 8; ++ni)
#pragma unroll
                for (int r = 0; r < 4; ++r) {
                    float v = acc[mi][ni][r];
                    float sil = v * fast_rcp(1.f + __expf(-v));
                    sm[(mi * 16 + lq * 4 + r) * PADI + (wn - 256) + ni * 16 + lr] =
                        f2bf(sil);
                }
    }
    __syncthreads();
    for (int i = tid; i < 2048; i += 256) {
        int row = i >> 5, col = (i & 31) * 8;
        us8 v = *(const us8*)&sm[row * PADI + col];
        *(us8*)&zs[(size_t)(mBase + row) * DI + col] = v;
    }
}

// ---------------------------------------------------------------------------
// FUSED: coalesced u_pre staging -> in-LDS conv+SiLU -> xproj GEMM ->
// scan1 with local-y.  Db tile HALVED (32 rows, ping-pong): GEMM-A ->
// scan-A || conv-B -> GEMM-B -> scan-B.  LDS 39424 B -> 4 blocks/CU.
// Bitwise-identical results to the 64-row-tile version (same MFMA shapes,
// same K order, same scan order).
// ---------------------------------------------------------------------------
__global__ __launch_bounds__(256, 4) void k_xp_scan1(
        const bf16_t* __restrict__ u_pre, const bf16_t* __restrict__ xwb,
        const float* __restrict__ cw, const float* __restrict__ cb,
        const float* __restrict__ dtw, const float* __restrict__ dtb,
        const float* __restrict__ Alog, const float* __restrict__ Dpv,
        float* __restrict__ dtc, float* __restrict__ Q,
        float* __restrict__ sdtb, bf16_t* __restrict__ ybase) {
    __shared__ bf16_t As[CHT * PADI];   // 33792 B
    __shared__ float  Db[32 * PADD];    // 5632 B (half-chunk xproj tile)
    int tid = threadIdx.x;
    size_t tokBase = (size_t)blockIdx.x * CHT;
    int b  = (int)(tokBase >> 13);
    int p0 = (int)(tokBase & (Lz - 1));
    int c  = p0 >> 6;
    int d  = tid;

    // halo (3 tokens before chunk; p0 is 0 or >=64)
    float hx3 = 0.f, hx2 = 0.f, hx1 = 0.f;
    if (p0 != 0) {
        size_t hb = tokBase * DI + d;
        hx3 = bf2f(u_pre[hb - 3 * DI]);
        hx2 = bf2f(u_pre[hb - 2 * DI]);
        hx1 = bf2f(u_pre[hb - 1 * DI]);
    }
    // coalesced staging of raw u_pre tile (all 64 rows)
    for (int i = tid; i < 2048; i += 256) {
        int row = i >> 5, col = (i & 31) * 8;
        us8 v = *(const us8*)&u_pre[(tokBase + row) * DI + col];
        *(us8*)&As[row * PADI + col] = v;
    }
    __syncthreads();

    // --- conv(k=4)+SiLU, first 32 rows (column-private) ---
    float cw0 = cw[d*4+0], cw1 = cw[d*4+1], cw2 = cw[d*4+2], cw3 = cw[d*4+3];
    float cbb = cb[d];
    float x3 = hx3, x2 = hx2, x1 = hx1;
#pragma unroll 8
    for (int t = 0; t < 32; ++t) {
        float x0 = bf2f(As[t * PADI + d]);
        float conv = cbb + cw0*x3 + cw1*x2 + cw2*x1 + cw3*x0;
        float sil = conv * fast_rcp(1.f + __expf(-conv));
        As[t * PADI + d] = f2bf(sil);
        x3 = x2; x2 = x1; x1 = x0;
    }
    __syncthreads();

    // --- persistent scan state (lives across both halves) ---
    float w[DTR];
#pragma unroll
    for (int r = 0; r < DTR; ++r) w[r] = dtw[d * DTR + r];
    float bb = dtb[d];
    float dp = Dpv[d];
    float a0;
    bool fast;
    {   // a[] scoped: only a0 stays live in the fast path
        float aa[DS];
        const float4* ap = (const float4*)(Alog + d * DS);
#pragma unroll
        for (int s4 = 0; s4 < 4; ++s4) {
            float4 av = ap[s4];
            aa[s4*4+0] = -__expf(av.x); aa[s4*4+1] = -__expf(av.y);
            aa[s4*4+2] = -__expf(av.z); aa[s4*4+3] = -__expf(av.w);
        }
        a0 = aa[0];
        fast = true;
#pragma unroll
        for (int s = 1; s < DS; ++s) {
            float ref = a0 * (float)(s + 1);
            fast = fast && (fabsf(aa[s] - ref) <= 1e-5f * fabsf(ref) + 1e-7f);
        }
    }
    float q[DS];
#pragma unroll
    for (int s = 0; s < DS; ++s) q[s] = 0.f;
    float sdt = 0.f;

    // GEMM wave mapping: wave owns one 16-row m-tile and two 16-col n-tiles
    int wave = tid >> 6, lane = tid & 63;
    int lr = lane & 15, lq = lane >> 4;
    int mt = (wave & 1) * 16;
    int np = (wave >> 1) * 32;
    const bf16_t* Bpx = xwb + (size_t)(np + lr) * DI + lq * 8;

    auto do_half = [&](int rbase, bool convB) {
        // --- xproj GEMM: Db[32 x 40] = u rows rbase..rbase+31 @ xw^T ---
        {
            f4 zf = {0.f, 0.f, 0.f, 0.f};
            f4 acc0 = zf, acc1 = zf;
#pragma unroll
            for (int kk = 0; kk < DI; kk += 32) {
                bf8 af = *(const bf8*)&As[(rbase + mt + lr) * PADI + lq * 8 + kk];
                bf8 b0 = *(const bf8*)(Bpx + kk);
                bf8 b1 = *(const bf8*)(Bpx + (size_t)16 * DI + kk);
                acc0 = __builtin_amdgcn_mfma_f32_16x16x32_bf16(af, b0, acc0, 0, 0, 0);
                acc1 = __builtin_amdgcn_mfma_f32_16x16x32_bf16(af, b1, acc1, 0, 0, 0);
            }
#pragma unroll
            for (int r = 0; r < 4; ++r) {
                int row = mt + lq * 4 + r;
                int c0 = np + lr;
                if (c0 < NDBL) Db[row * PADD + c0] = acc0[r];
                int c1 = np + 16 + lr;
                if (c1 < NDBL) Db[row * PADD + c1] = acc1[r];
            }
        }
        __syncthreads();
        // dtc (dt cols 0..7 + C cols 24..39 -> 24 cols) for this half
        for (int i = tid; i < 32 * 24; i += 256) {
            int row = i / 24, cc = i - row * 24;
            dtc[(tokBase + rbase + row) * 24 + cc] =
                Db[row * PADD + (cc < 8 ? cc : cc + 16)];
        }
        // conv second half overlaps with scan-A (disjoint As rows)
        if (convB) {
#pragma unroll 8
            for (int t = 32; t < 64; ++t) {
                float x0 = bf2f(As[t * PADI + d]);
                float conv = cbb + cw0*x3 + cw1*x2 + cw2*x1 + cw3*x0;
                float sil = conv * fast_rcp(1.f + __expf(-conv));
                As[t * PADI + d] = f2bf(sil);
                x3 = x2; x2 = x1; x1 = x0;
            }
        }
        // --- scan over this half ---
        bf16_t* yp = ybase + (tokBase + rbase) * DI + d;
        if (fast) {
#pragma unroll 4
            for (int t = 0; t < 32; ++t) {
                float4 r0 = *(const float4*)&Db[t * PADD + 0];
                float4 r1 = *(const float4*)&Db[t * PADD + 4];
                float xv = bb + r0.x*w[0] + r0.y*w[1] + r0.z*w[2] + r0.w*w[3]
                              + r1.x*w[4] + r1.y*w[5] + r1.z*w[6] + r1.w*w[7];
                float dtv = (xv > 20.f) ? xv : __logf(1.f + __expf(xv));
                sdt += dtv;
                float uv = bf2f(As[(rbase + t) * PADI + d]);
                float dtu = dtv * uv;
                float e1 = __expf(dtv * a0);
                float dA[DS];
                pow_tree(e1, dA);
                float bv[DS], cv[DS];
                *(float4*)&bv[0]  = *(const float4*)&Db[t * PADD + 8];
                *(float4*)&bv[4]  = *(const float4*)&Db[t * PADD + 12];
                *(float4*)&bv[8]  = *(const float4*)&Db[t * PADD + 16];
                *(float4*)&bv[12] = *(const float4*)&Db[t * PADD + 20];
                *(float4*)&cv[0]  = *(const float4*)&Db[t * PADD + 24];
                *(float4*)&cv[4]  = *(const float4*)&Db[t * PADD + 28];
                *(float4*)&cv[8]  = *(const float4*)&Db[t * PADD + 32];
                *(float4*)&cv[12] = *(const float4*)&Db[t * PADD + 36];
                float y0 = 0.f, y1 = 0.f, y2 = 0.f, y3 = 0.f;
#pragma unroll
                for (int s = 0; s < DS; s += 4) {
                    q[s]   = q[s]   * dA[s]   + dtu * bv[s];
                    q[s+1] = q[s+1] * dA[s+1] + dtu * bv[s+1];
                    q[s+2] = q[s+2] * dA[s+2] + dtu * bv[s+2];
                    q[s+3] = q[s+3] * dA[s+3] + dtu * bv[s+3];
                    y0 += q[s]   * cv[s];
                    y1 += q[s+1] * cv[s+1];
                    y2 += q[s+2] * cv[s+2];
                    y3 += q[s+3] * cv[s+3];
                }
                float y = (y0 + y1) + (y2 + y3);
                yp[(size_t)t * DI] = f2bf(y + uv * dp);
            }
        } else {
            // rare path: recompute a[] locally (keeps fast path lean)
            float av[DS];
            const float4* ap = (const float4*)(Alog + d * DS);
#pragma unroll
            for (int s4 = 0; s4 < 4; ++s4) {
                float4 avv = ap[s4];
                av[s4*4+0] = -__expf(avv.x); av[s4*4+1] = -__expf(avv.y);
                av[s4*4+2] = -__expf(avv.z); av[s4*4+3] = -__expf(avv.w);
            }
            for (int t = 0; t < 32; ++t) {
                float4 r0 = *(const float4*)&Db[t * PADD + 0];
                float4 r1 = *(const float4*)&Db[t * PADD + 4];
                float xv = bb + r0.x*w[0] + r0.y*w[1] + r0.z*w[2] + r0.w*w[3]
                              + r1.x*w[4] + r1.y*w[5] + r1.z*w[6] + r1.w*w[7];
                float dtv = (xv > 20.f) ? xv : __logf(1.f + __expf(xv));
                sdt += dtv;
                float uv = bf2f(As[(rbase + t) * PADI + d]);
                float dtu = dtv * uv;
                float bv[DS], cv[DS];
                *(float4*)&bv[0]  = *(const float4*)&Db[t * PADD + 8];
                *(float4*)&bv[4]  = *(const float4*)&Db[t * PADD + 12];
                *(float4*)&bv[8]  = *(const float4*)&Db[t * PADD + 16];
                *(float4*)&bv[12] = *(const float4*)&Db[t * PADD + 20];
                *(float4*)&cv[0]  = *(const float4*)&Db[t * PADD + 24];
                *(float4*)&cv[4]  = *(const float4*)&Db[t * PADD + 28];
                *(float4*)&cv[8]  = *(const float4*)&Db[t * PADD + 32];
                *(float4*)&cv[12] = *(const float4*)&Db[t * PADD + 36];
                float y = 0.f;
#pragma unroll
                for (int s = 0; s < DS; ++s) {
                    float dAv = __expf(dtv * av[s]);
                    q[s] = q[s] * dAv + dtu * bv[s];
                    y += q[s] * cv[s];
                }
                yp[(size_t)t * DI] = f2bf(y + uv * dp);
            }
        }
        __syncthreads();   // Db reads + conv-B writes done before next GEMM
    };
    do_half(0, true);
    do_half(32, false);

    size_t o = ((size_t)(b * NCH + c) * DI + d) * DS;
#pragma unroll
    for (int s = 0; s < DS; s += 4)
        *(float4*)&Q[o + s] = make_float4(q[s], q[s+1], q[s+2], q[s+3]);
    sdtb[(size_t)(b * NCH + c) * DI + d] = sdt;
}

// ---------------------------------------------------------------------------
// Phase 2: decay from sdt (exact: prod exp(dtv*a) == exp(a*sum dtv)).
// Q[c] overwritten in place with chunk entry state. 16-deep prefetch.
// 128-thread blocks -> 256 blocks spread over all CUs.
// ---------------------------------------------------------------------------
__global__ __launch_bounds__(128) void k_scan2(float* __restrict__ Q,
                                               const float* __restrict__ sdtb,
                                               const float* __restrict__ Alog) {
    int gid = blockIdx.x * 128 + threadIdx.x;   // Bz*DI*DS threads
    int b = gid >> 12, r = gid & 4095;          // r = d*16 + s
    int d = r >> 4, s = r & 15;
    float a = -__expf(Alog[d * DS + s]);
    const size_t stride = (size_t)DI * DS;
    size_t base = (size_t)b * NCH * stride + r;
    const float* sp = sdtb + (size_t)b * NCH * DI + d;
    float hh = 0.f;
    for (int g = 0; g < NCH / 16; ++g) {
        float qq[16], ee[16];
#pragma unroll
        for (int j = 0; j < 16; ++j)
            qq[j] = Q[base + (size_t)(g * 16 + j) * stride];
#pragma unroll
        for (int j = 0; j < 16; ++j)
            ee[j] = __expf(a * sp[(size_t)(g * 16 + j) * DI]);
#pragma unroll
        for (int j = 0; j < 16; ++j) {
            size_t o = base + (size_t)(g * 16 + j) * stride;
            Q[o] = hh;
            hh = ee[j] * hh + qq[j];
        }
    }
}

// ---------------------------------------------------------------------------
// FUSED: correction + gate -> y tile -> out-GEMM h += y @ out_w^T.
// y_t = ybase_t + sum_s C_t[s]*H0[s]*exp(a[s]*cdt_t); out = y * zs.
// (pow_tree form kept verbatim — Horner reordering shifted absmax by 1 ULP
//  past the pass threshold in round 1.)
// ---------------------------------------------------------------------------
__global__ __launch_bounds__(256, 4) void k_corr_out(
        const float* __restrict__ dtc, const bf16_t* __restrict__ ybase,
        const bf16_t* __restrict__ zs,
        const float* __restrict__ dtw, const float* __restrict__ dtb,
        const float* __restrict__ Alog, const float* __restrict__ H0,
        const bf16_t* __restrict__ owb, float* __restrict__ h) {
    __shared__ float epit[CHT * 132];  // 33792 B; aliased as bf16 y tile
    __shared__ float Dt8[CHT * 8];     // 2048 B
    __shared__ float Cs[CHT * DS];     // 4096 B
    bf16_t* yt = (bf16_t*)epit;

    int tid = threadIdx.x;
    size_t tokBase = (size_t)blockIdx.x * CHT;
    int b  = (int)(tokBase >> 13);
    int p0 = (int)(tokBase & (Lz - 1));
    int c  = p0 >> 6;

    for (int i = tid; i < CHT * 24; i += 256) {
        float v = dtc[tokBase * 24 + i];
        int t = i / 24, col = i - t * 24;
        if (col < 8) Dt8[t * 8 + col] = v;
        else         Cs[t * DS + (col - 8)] = v;
    }
    __syncthreads();

    // --- correction + gating (thread = d) ---
    {
        int d = tid;
        float w[DTR];
#pragma unroll
        for (int r = 0; r < DTR; ++r) w[r] = dtw[d * DTR + r];
        float bb = dtb[d];
        float a[DS], gh[DS];
        const float4* ap = (const float4*)(Alog + d * DS);
#pragma unroll
        for (int s4 = 0; s4 < 4; ++s4) {
            float4 av = ap[s4];
            a[s4*4+0] = -__expf(av.x); a[s4*4+1] = -__expf(av.y);
            a[s4*4+2] = -__expf(av.z); a[s4*4+3] = -__expf(av.w);
        }
        size_t ho = ((size_t)(b * NCH + c) * DI + d) * DS;
#pragma unroll
        for (int s = 0; s < DS; s += 4) {
            float4 hv = *(const float4*)&H0[ho + s];
            gh[s] = hv.x; gh[s+1] = hv.y; gh[s+2] = hv.z; gh[s+3] = hv.w;
        }
        float a0 = a[0];
        bool fast = true;
#pragma unroll
        for (int s = 1; s < DS; ++s) {
            float ref = a0 * (float)(s + 1);
            fast = fast && (fabsf(a[s] - ref) <= 1e-5f * fabsf(ref) + 1e-7f);
        }
        const bf16_t* yp = ybase + tokBase * DI + d;
        const bf16_t* zp = zs + tokBase * DI + d;
        float cdt = 0.f;
        float yc[4], zc[4];
#pragma unroll
        for (int j = 0; j < 4; ++j) {
            yc[j] = bf2f(yp[(size_t)j * DI]);
            zc[j] = bf2f(zp[(size_t)j * DI]);
        }
        for (int g = 0; g < CHT / 4; ++g) {
            float yn[4] = {0,0,0,0}, zn[4] = {0,0,0,0};
            if (g + 1 < CHT / 4) {
#pragma unroll
                for (int j = 0; j < 4; ++j) {
                    yn[j] = bf2f(yp[(size_t)((g + 1) * 4 + j) * DI]);
                    zn[j] = bf2f(zp[(size_t)((g + 1) * 4 + j) * DI]);
                }
            }
#pragma unroll
            for (int j = 0; j < 4; ++j) {
                int t = g * 4 + j;
                float4 r0 = *(const float4*)&Dt8[t * 8];
                float4 r1 = *(const float4*)&Dt8[t * 8 + 4];
                float xv = bb + r0.x*w[0] + r0.y*w[1] + r0.z*w[2] + r0.w*w[3]
                              + r1.x*w[4] + r1.y*w[5] + r1.z*w[6] + r1.w*w[7];
                float dtv = (xv > 20.f) ? xv : __logf(1.f + __expf(xv));
                cdt += dtv;
                float cv[DS];
                *(float4*)&cv[0]  = *(const float4*)&Cs[t * DS + 0];
                *(float4*)&cv[4]  = *(const float4*)&Cs[t * DS + 4];
                *(float4*)&cv[8]  = *(const float4*)&Cs[t * DS + 8];
                *(float4*)&cv[12] = *(const float4*)&Cs[t * DS + 12];
                float corr0 = 0.f, corr1 = 0.f, corr2 = 0.f, corr3 = 0.f;
                if (fast) {
                    float e1 = __expf(a0 * cdt);
                    float dA[DS];
                    pow_tree(e1, dA);
#pragma unroll
                    for (int s = 0; s < DS; s += 4) {
                        corr0 += cv[s]   * (gh[s]   * dA[s]);
                        corr1 += cv[s+1] * (gh[s+1] * dA[s+1]);
                        corr2 += cv[s+2] * (gh[s+2] * dA[s+2]);
                        corr3 += cv[s+3] * (gh[s+3] * dA[s+3]);
                    }
                } else {
#pragma unroll
                    for (int s = 0; s < DS; ++s)
                        corr0 += cv[s] * (gh[s] * __expf(a[s] * cdt));
                }
                float y = yc[j] + ((corr0 + corr1) + (corr2 + corr3));
                yt[t * PADI + d] = f2bf(y * zc[j]);
            }
#pragma unroll
            for (int j = 0; j < 4; ++j) { yc[j] = yn[j]; zc[j] = zn[j]; }
        }
    }
    __syncthreads();

    // --- out-GEMM: h[64 x 128] += y[64 x 256] @ out_w^T ---
    int wave = tid >> 6, lane = tid & 63;
    int lr = lane & 15, lq = lane >> 4;
    int wm = wave * 16;
    f4 zf = {0.f, 0.f, 0.f, 0.f};
    f4 acc[8];
#pragma unroll
    for (int ni = 0; ni < 8; ++ni) acc[ni] = zf;
    const bf16_t* Bp = owb + (size_t)lr * DI + lq * 8;
#pragma unroll
    for (int kk = 0; kk < DI; kk += 32) {
        bf8 af = *(const bf8*)&yt[(wm + lr) * PADI + lq * 8 + kk];
        bf8 bq[8];
#pragma unroll
        for (int ni = 0; ni < 8; ++ni)
            bq[ni] = *(const bf8*)(Bp + (size_t)ni * 16 * DI + kk);
#pragma unroll
        for (int ni = 0; ni < 8; ++ni)
            acc[ni] = __builtin_amdgcn_mfma_f32_16x16x32_bf16(
                af, bq[ni], acc[ni], 0, 0, 0);
    }
    __syncthreads();   // yt reads done; epit may be overwritten
#pragma unroll
    for (int ni = 0; ni < 8; ++ni)
#pragma unroll
        for (int r = 0; r < 4; ++r)
            epit[(wm + lq * 4 + r) * 132 + ni * 16 + lr] = acc[ni][r];
    __syncthreads();
    for (int i = tid; i < 2048; i += 256) {
        int row = i >> 5, col = (i & 31) * 4;
        float4 v = *(const float4*)&epit[row * 132 + col];
        float4 old = *(const float4*)&h[(tokBase + row) * DM + col];
        old.x += v.x; old.y += v.y; old.z += v.z; old.w += v.w;
        *(float4*)&h[(tokBase + row) * DM + col] = old;
    }
}

// ---------------------------------------------------------------------------
__global__ __launch_bounds__(256) void k_final(float* __restrict__ h,
                                               const float* __restrict__ w,
                                               const float* __restrict__ bias,
                                               float* __restrict__ hg) {
    __shared__ float sbuf[DM];
    int t    = blockIdx.x * 16 + (threadIdx.x >> 4);
    int lane = threadIdx.x & 15;
    int b    = t >> 13;
    if (threadIdx.x < DM) sbuf[threadIdx.x] = 0.f;
    __syncthreads();
    float4* hp = (float4*)(h + (size_t)t * DM + lane * 8);
    float4 v0 = hp[0], v1 = hp[1];
    float s = v0.x + v0.y + v0.z + v0.w + v1.x + v1.y + v1.z + v1.w;
    float q = v0.x*v0.x + v0.y*v0.y + v0.z*v0.z + v0.w*v0.w +
              v1.x*v1.x + v1.y*v1.y + v1.z*v1.z + v1.w*v1.w;
#pragma unroll
    for (int off = 1; off < 16; off <<= 1) {
        s += __shfl_xor(s, off);
        q += __shfl_xor(q, off);
    }
    float mean = s * (1.f / DM);
    float var  = q * (1.f / DM) - mean * mean;
    float rstd = rsqrtf(var + 1e-5f);
    const float4* wp = (const float4*)(w + lane * 8);
    const float4* bp = (const float4*)(bias + lane * 8);
    float4 w0 = wp[0], w1 = wp[1], b0 = bp[0], b1 = bp[1];
    float4 o0, o1;
    o0.x = (v0.x - mean) * rstd * w0.x + b0.x;
    o0.y = (v0.y - mean) * rstd * w0.y + b0.y;
    o0.z = (v0.z - mean) * rstd * w0.z + b0.z;
    o0.w = (v0.w - mean) * rstd * w0.w + b0.w;
    o1.x = (v1.x - mean) * rstd * w1.x + b1.x;
    o1.y = (v1.y - mean) * rstd * w1.y + b1.y;
    o1.z = (v1.z - mean) * rstd * w1.z + b1.z;
    o1.w = (v1.w - mean) * rstd * w1.w + b1.w;
    hp[0] = o0; hp[1] = o1;
    int dbase = lane * 8;
    atomicAdd(&sbuf[dbase + 0], o0.x); atomicAdd(&sbuf[dbase + 1], o0.y);
    atomicAdd(&sbuf[dbase + 2], o0.z); atomicAdd(&sbuf[dbase + 3], o0.w);
    atomicAdd(&sbuf[dbase + 4], o1.x); atomicAdd(&sbuf[dbase + 5], o1.y);
    atomicAdd(&sbuf[dbase + 6], o1.z); atomicAdd(&sbuf[dbase + 7], o1.w);
    __syncthreads();
    if (threadIdx.x < DM)
        atomicAdd(&hg[b * DM + threadIdx.x], sbuf[threadIdx.x] * (1.f / Lz));
}

// ---------------------------------------------------------------------------
extern "C" void kernel_launch(void* const* d_in, const int* in_sizes, int n_in,
                              void* d_out, int out_size, void* d_ws, size_t ws_size,
                              hipStream_t stream) {
    const float* x       = (const float*)d_in[0];
    const float* proj_w  = (const float*)d_in[1];
    const float* proj_b  = (const float*)d_in[2];
    const float* ln_w    = (const float*)d_in[3];
    const float* ln_b    = (const float*)d_in[4];
    const float* in_w    = (const float*)d_in[5];
    const float* conv_w  = (const float*)d_in[6];
    const float* conv_b  = (const float*)d_in[7];
    const float* xproj_w = (const float*)d_in[8];
    const float* dt_w    = (const float*)d_in[9];
    const float* dt_b    = (const float*)d_in[10];
    const float* A_log   = (const float*)d_in[11];
    const float* Dp      = (const float*)d_in[12];
    const float* out_w   = (const float*)d_in[13];
    const float* lnout_w = (const float*)d_in[14];
    const float* lnout_b = (const float*)d_in[15];

    float* out = (float*)d_out;
    float* h   = out;                        // [BL][128] lives in d_out
    float* hg  = out + (size_t)BLz * DM;     // [B][128]

    // Workspace layout (~108 MiB) — identical to the verified round-7 layout.
    char* ws = (char*)d_ws;
    bf16_t* u_pre = (bf16_t*)(ws);                    // 32 MiB
    bf16_t* zs    = (bf16_t*)(ws + 33554432ULL);      // 32 MiB
    bf16_t* ybase = (bf16_t*)(ws + 67108864ULL);      // 32 MiB
    float*  dtc   = (float*) (ws + 100663296ULL);     // 6 MiB  (BL*24*4)
    float*  Q     = (float*) (ws + 106954752ULL);     // 16 MiB
    float*  sdtb  = (float*) (ws + 123731968ULL);     // 1 MiB
    bf16_t* inwb  = (bf16_t*)(ws + 124780544ULL);     // 512 KiB
    bf16_t* owb   = (bf16_t*)(ws + 125304832ULL);     // 256 KiB
    bf16_t* xwb   = (bf16_t*)(ws + 125566976ULL);     // 128 KiB

    k_wconv<<<1024, 256, 0, stream>>>(in_w, out_w, xproj_w, inwb, owb, xwb, hg);
    k_inproj<<<BLz / 2, 256, 0, stream>>>(x, proj_w, proj_b, h);

    for (int i = 0; i < DEPTHN; ++i) {
        k_lnin<<<BLz / 64, 256, 0, stream>>>(
            h, ln_w + i * DM, ln_b + i * DM,
            inwb + (size_t)i * 512 * DM, u_pre, zs);
        k_xp_scan1<<<BLz / CHT, 256, 0, stream>>>(
            u_pre, xwb + (size_t)i * 64 * DI,
            conv_w + i * DI * 4, conv_b + i * DI,
            dt_w + i * DI * DTR, dt_b + i * DI, A_log + i * DI * DS,
            Dp + i * DI, dtc, Q, sdtb, ybase);
        k_scan2<<<(Bz * DI * DS) / 128, 128, 0, stream>>>(
            Q, sdtb, A_log + i * DI * DS);
        k_corr_out<<<BLz / CHT, 256, 0, stream>>>(
            dtc, ybase, zs,
            dt_w + i * DI * DTR, dt_b + i * DI,
            A_log + i * DI * DS, Q,
            owb + (size_t)i * DM * DI, h);
    }

    k_final<<<BLz / 16, 256, 0, stream>>>(h, lnout_w, lnout_b, hg);
}

// Round 4
// 882.173 us; speedup vs baseline: 1.1706x; 1.1706x over previous
//
#include <hip/hip_runtime.h>
#include <hip/hip_bf16.h>
#include <math.h>

// Problem constants (MambaEncoder)
#define Bz     8
#define Lz     8192
#define DM     128      // d_model
#define DI     256      // d_inner
#define DS     16       // d_state
#define DTR    8        // dt_rank
#define NDBL   40       // DTR + 2*DS
#define DEPTHN 4
#define BLz    (Bz*Lz)  // 65536 tokens
#define CHT    64       // scan chunk length == M-tile
#define NCH    (Lz/CHT) // 128 chunks per sequence
#define PADI   264      // bf16 tile row stride
#define PADD   44       // f32 Db row stride

typedef unsigned short bf16_t;
typedef __attribute__((ext_vector_type(8))) __bf16 bf8;
typedef __attribute__((ext_vector_type(4))) float f4;
typedef __attribute__((ext_vector_type(8))) unsigned short us8;

__device__ __forceinline__ float bf2f(bf16_t u) {
    return __uint_as_float(((unsigned)u) << 16);
}
__device__ __forceinline__ bf16_t f2bf(float f) {
    unsigned u = __float_as_uint(f);
    u = u + 0x7FFFu + ((u >> 16) & 1u);   // round-to-nearest-even
    return (bf16_t)(u >> 16);
}
__device__ __forceinline__ float fast_rcp(float x) {
    return __builtin_amdgcn_rcpf(x);
}

// dA power tree: dA[s] = e1^(s+1), depth 4.
__device__ __forceinline__ void pow_tree(float e1, float dA[DS]) {
    float e2 = e1 * e1, e3 = e2 * e1, e4 = e2 * e2;
    float e8 = e4 * e4;
    dA[0] = e1;       dA[1] = e2;       dA[2] = e3;       dA[3] = e4;
    dA[4] = e4 * e1;  dA[5] = e4 * e2;  dA[6] = e4 * e3;  dA[7] = e8;
    dA[8] = e8 * e1;  dA[9] = e8 * e2;  dA[10] = e8 * e3; dA[11] = e8 * e4;
    dA[12] = e8 * dA[4]; dA[13] = e8 * dA[5]; dA[14] = e8 * dA[6];
    dA[15] = e8 * e8;
}

// ---------------------------------------------------------------------------
// Convert weights fp32 -> bf16 (xproj padded 40->64 rows) + zero hg.
// ---------------------------------------------------------------------------
__global__ __launch_bounds__(256) void k_wconv(const float* __restrict__ inw,
                                               const float* __restrict__ ow,
                                               const float* __restrict__ xw,
                                               bf16_t* __restrict__ inwb,
                                               bf16_t* __restrict__ owb,
                                               bf16_t* __restrict__ xwb,
                                               float* __restrict__ hg) {
    int i = blockIdx.x * 256 + threadIdx.x;
    if (i < Bz * DM) hg[i] = 0.f;
    if (i < DEPTHN * 512 * DM) inwb[i] = f2bf(inw[i]);
    if (i < DEPTHN * DM * DI)  owb[i]  = f2bf(ow[i]);
    if (i < DEPTHN * 64 * DI) {
        int layer = i >> 14, rk = i & 16383, r = rk >> 8, k = rk & 255;
        xwb[i] = (r < NDBL) ? f2bf(xw[((size_t)layer * NDBL + r) * DI + k]) : (bf16_t)0;
    }
}

// ---------------------------------------------------------------------------
__global__ __launch_bounds__(256) void k_inproj(const float* __restrict__ x,
                                                const float* __restrict__ pw,
                                                const float* __restrict__ pb,
                                                float* __restrict__ h) {
    int t = blockIdx.x * 2 + (threadIdx.x >> 7);
    int d = threadIdx.x & 127;
    int b = t >> 13, l = t & (Lz - 1);
    float acc = pb[d];
#pragma unroll
    for (int c = 0; c < 3; ++c)
        acc += x[(size_t)(b * 3 + c) * Lz + l] * pw[d * 3 + c];
    h[(size_t)t * DM + d] = acc;
}

// ---------------------------------------------------------------------------
// FUSED per-64-token chunk: LayerNorm (64 rows + 3 halo rows) -> in-proj
// GEMM (u cols direct to As LDS; halo u via an EXTRA MFMA m-tile anchored at
// row 51 so rows 51+lr cover halo rows 64..66 -> bit-identical to the u_pre
// MFMA chain of the unfused kernel) -> z silu -> zs -> conv+SiLU -> xproj
// GEMM -> scan1.  All main-path numerics bit-identical to round-0.
// LDS: As 33792 + Rb 18496 = 52288 B -> 3 blocks/CU.
// ---------------------------------------------------------------------------
__global__ __launch_bounds__(256, 3) void k_lnscan(
        const float* __restrict__ h,
        const float* __restrict__ lw, const float* __restrict__ lb,
        const bf16_t* __restrict__ inwb, const bf16_t* __restrict__ xwb,
        const float* __restrict__ cw, const float* __restrict__ cb,
        const float* __restrict__ dtw, const float* __restrict__ dtb,
        const float* __restrict__ Alog, const float* __restrict__ Dpv,
        bf16_t* __restrict__ zs, float* __restrict__ dtc,
        float* __restrict__ Q, float* __restrict__ sdtb,
        bf16_t* __restrict__ ybase) {
    __shared__ bf16_t As[CHT * PADI];   // 33792 B: u tile (conv'd in place)
    __shared__ char   Rb[18496];        // xs(67x136 bf16) -> zt(64x136) -> Db(64x44 f32)
    bf16_t* xs = (bf16_t*)Rb;
    bf16_t* zt = (bf16_t*)Rb;
    float*  Db = (float*)Rb;

    int tid = threadIdx.x;
    size_t tokBase = (size_t)blockIdx.x * CHT;
    int b  = (int)(tokBase >> 13);
    int p0 = (int)(tokBase & (Lz - 1));
    int c  = p0 >> 6;
    int d  = tid;

    // --- P0: LayerNorm 64 chunk rows + 3 halo rows (xs rows 64..66) ---
#pragma unroll
    for (int p = 0; p < 5; ++p) {
        int row = p * 16 + (tid >> 4);
        if (row >= 67) continue;                 // whole 16-lane groups skip
        int lane = tid & 15;
        if (row >= 64 && p0 == 0) {              // no halo at seq start: zero
            ushort4 z4 = {0, 0, 0, 0};
            *(ushort4*)&xs[row * 136 + lane * 8]     = z4;
            *(ushort4*)&xs[row * 136 + lane * 8 + 4] = z4;
            continue;
        }
        size_t tok = (row < 64) ? (tokBase + row) : (tokBase - 3 + (row - 64));
        const float4* hp = (const float4*)(h + tok * DM + lane * 8);
        float4 v0 = hp[0], v1 = hp[1];
        float s = v0.x + v0.y + v0.z + v0.w + v1.x + v1.y + v1.z + v1.w;
        float q = v0.x*v0.x + v0.y*v0.y + v0.z*v0.z + v0.w*v0.w +
                  v1.x*v1.x + v1.y*v1.y + v1.z*v1.z + v1.w*v1.w;
#pragma unroll
        for (int off = 1; off < 16; off <<= 1) {
            s += __shfl_xor(s, off);
            q += __shfl_xor(q, off);
        }
        float mean = s * (1.f / DM);
        float var  = q * (1.f / DM) - mean * mean;
        float rstd = rsqrtf(var + 1e-5f);
        const float4* wp = (const float4*)(lw + lane * 8);
        const float4* bp = (const float4*)(lb + lane * 8);
        float4 w0 = wp[0], w1 = wp[1], b0 = bp[0], b1 = bp[1];
        ushort4 o0, o1;
        o0.x = f2bf((v0.x - mean) * rstd * w0.x + b0.x);
        o0.y = f2bf((v0.y - mean) * rstd * w0.y + b0.y);
        o0.z = f2bf((v0.z - mean) * rstd * w0.z + b0.z);
        o0.w = f2bf((v0.w - mean) * rstd * w0.w + b0.w);
        o1.x = f2bf((v1.x - mean) * rstd * w1.x + b1.x);
        o1.y = f2bf((v1.y - mean) * rstd * w1.y + b1.y);
        o1.z = f2bf((v1.z - mean) * rstd * w1.z + b1.z);
        o1.w = f2bf((v1.w - mean) * rstd * w1.w + b1.w);
        *(ushort4*)&xs[row * 136 + lane * 8]     = o0;
        *(ushort4*)&xs[row * 136 + lane * 8 + 4] = o1;
    }
    __syncthreads();

    int wave = tid >> 6, lane = tid & 63;
    int lr = lane & 15, lq = lane >> 4;
    f4 zf = {0.f, 0.f, 0.f, 0.f};

    // --- P1: u-GEMM (cols 0..255, wave n-slice 64) -> As directly;
    //     fused halo m-tile (A rows 51+lr -> C rows 51..66, keep 64..66) ---
    float uh3 = 0.f, uh2 = 0.f, uh1 = 0.f;
    {
        int wn = wave * 64;
        f4 accu[4][4];
        f4 accH[4];
#pragma unroll
        for (int mi = 0; mi < 4; ++mi)
#pragma unroll
            for (int ni = 0; ni < 4; ++ni) accu[mi][ni] = zf;
#pragma unroll
        for (int ni = 0; ni < 4; ++ni) accH[ni] = zf;
        const bf16_t* Bp = inwb + (size_t)(wn + lr) * DM + lq * 8;
#pragma unroll
        for (int kk = 0; kk < DM; kk += 32) {
            bf8 af[4], afh, bq[4];
#pragma unroll
            for (int mi = 0; mi < 4; ++mi)
                af[mi] = *(const bf8*)&xs[(mi * 16 + lr) * 136 + lq * 8 + kk];
            afh = *(const bf8*)&xs[(51 + lr) * 136 + lq * 8 + kk];
#pragma unroll
            for (int ni = 0; ni < 4; ++ni)
                bq[ni] = *(const bf8*)(Bp + (size_t)ni * 16 * DM + kk);
#pragma unroll
            for (int mi = 0; mi < 4; ++mi)
#pragma unroll
                for (int ni = 0; ni < 4; ++ni)
                    accu[mi][ni] = __builtin_amdgcn_mfma_f32_16x16x32_bf16(
                        af[mi], bq[ni], accu[mi][ni], 0, 0, 0);
#pragma unroll
            for (int ni = 0; ni < 4; ++ni)
                accH[ni] = __builtin_amdgcn_mfma_f32_16x16x32_bf16(
                    afh, bq[ni], accH[ni], 0, 0, 0);
        }
#pragma unroll
        for (int mi = 0; mi < 4; ++mi)
#pragma unroll
            for (int ni = 0; ni < 4; ++ni)
#pragma unroll
                for (int r = 0; r < 4; ++r)
                    As[(mi * 16 + lq * 4 + r) * PADI + wn + ni * 16 + lr] =
                        f2bf(accu[mi][ni][r]);

        // halo rows 64..66 = (lq=3, r=1..3), lanes 48+lr hold col wn+ni*16+lr.
        // Thread d (this wave: wn <= d < wn+64) needs col d for rows 64..66.
        if (p0 != 0) {
            int src   = 48 + (d & 15);
            int nisel = (d >> 4) & 3;
            float hv[3];
#pragma unroll
            for (int j = 0; j < 3; ++j) {
                float v0 = __shfl(bf2f(f2bf(accH[0][j + 1])), src);
                float v1 = __shfl(bf2f(f2bf(accH[1][j + 1])), src);
                float v2 = __shfl(bf2f(f2bf(accH[2][j + 1])), src);
                float v3 = __shfl(bf2f(f2bf(accH[3][j + 1])), src);
                hv[j] = (nisel == 0) ? v0 : (nisel == 1) ? v1
                      : (nisel == 2) ? v2 : v3;
            }
            uh3 = hv[0]; uh2 = hv[1]; uh1 = hv[2];
        }
    }

    // --- P2: z-GEMM (cols 256..511) -> silu -> zs global via zt staging ---
    f4 accz[4][4];
    {
        int wnz = 256 + wave * 64;
#pragma unroll
        for (int mi = 0; mi < 4; ++mi)
#pragma unroll
            for (int ni = 0; ni < 4; ++ni) accz[mi][ni] = zf;
        const bf16_t* Bp = inwb + (size_t)(wnz + lr) * DM + lq * 8;
#pragma unroll
        for (int kk = 0; kk < DM; kk += 32) {
            bf8 af[4], bq[4];
#pragma unroll
            for (int mi = 0; mi < 4; ++mi)
                af[mi] = *(const bf8*)&xs[(mi * 16 + lr) * 136 + lq * 8 + kk];
#pragma unroll
            for (int ni = 0; ni < 4; ++ni)
                bq[ni] = *(const bf8*)(Bp + (size_t)ni * 16 * DM + kk);
#pragma unroll
            for (int mi = 0; mi < 4; ++mi)
#pragma unroll
                for (int ni = 0; ni < 4; ++ni)
                    accz[mi][ni] = __builtin_amdgcn_mfma_f32_16x16x32_bf16(
                        af[mi], bq[ni], accz[mi][ni], 0, 0, 0);
        }
    }
    __syncthreads();   // all xs reads done; zt may overwrite xs region

    // half A: waves 0,1 hold zs cols 0..127
    if (wave < 2) {
#pragma unroll
        for (int mi = 0; mi < 4; ++mi)
#pragma unroll
            for (int ni = 0; ni < 4; ++ni)
#pragma unroll
                for (int r = 0; r < 4; ++r) {
                    float v = accz[mi][ni][r];
                    float sil = v * fast_rcp(1.f + __expf(-v));
                    zt[(mi * 16 + lq * 4 + r) * 136 + wave * 64 + ni * 16 + lr] =
                        f2bf(sil);
                }
    }
    __syncthreads();
    for (int i = tid; i < 1024; i += 256) {
        int row = i >> 4, col = (i & 15) * 8;
        us8 v = *(const us8*)&zt[row * 136 + col];
        *(us8*)&zs[(tokBase + row) * DI + col] = v;
    }
    __syncthreads();
    // half B: waves 2,3 hold zs cols 128..255
    if (wave >= 2) {
#pragma unroll
        for (int mi = 0; mi < 4; ++mi)
#pragma unroll
            for (int ni = 0; ni < 4; ++ni)
#pragma unroll
                for (int r = 0; r < 4; ++r) {
                    float v = accz[mi][ni][r];
                    float sil = v * fast_rcp(1.f + __expf(-v));
                    zt[(mi * 16 + lq * 4 + r) * 136 + (wave - 2) * 64 + ni * 16 + lr] =
                        f2bf(sil);
                }
    }
    __syncthreads();
    for (int i = tid; i < 1024; i += 256) {
        int row = i >> 4, col = (i & 15) * 8;
        us8 v = *(const us8*)&zt[row * 136 + col];
        *(us8*)&zs[(tokBase + row) * DI + 128 + col] = v;
    }
    __syncthreads();   // zt dead; Db may reuse R region after next sync

    // --- conv(k=4)+SiLU in place (column-private), all 64 rows ---
    {
        float cw0 = cw[d*4+0], cw1 = cw[d*4+1], cw2 = cw[d*4+2], cw3 = cw[d*4+3];
        float cbb = cb[d];
        float x3 = uh3, x2 = uh2, x1 = uh1;
#pragma unroll 8
        for (int t = 0; t < CHT; ++t) {
            float x0 = bf2f(As[t * PADI + d]);
            float conv = cbb + cw0*x3 + cw1*x2 + cw2*x1 + cw3*x0;
            float sil = conv * fast_rcp(1.f + __expf(-conv));
            As[t * PADI + d] = f2bf(sil);
            x3 = x2; x2 = x1; x1 = x0;
        }
    }
    __syncthreads();

    // --- xproj GEMM: Db[64 x 40] = u @ xw^T (round-0 monolithic) ---
    {
        int wm = wave * 16;
        f4 acc[4];
#pragma unroll
        for (int ni = 0; ni < 4; ++ni) acc[ni] = zf;
        const bf16_t* Bp = xwb + (size_t)lr * DI + lq * 8;
#pragma unroll
        for (int kk = 0; kk < DI; kk += 32) {
            bf8 af = *(const bf8*)&As[(wm + lr) * PADI + lq * 8 + kk];
            bf8 bq[4];
#pragma unroll
            for (int ni = 0; ni < 4; ++ni)
                bq[ni] = *(const bf8*)(Bp + (size_t)ni * 16 * DI + kk);
#pragma unroll
            for (int ni = 0; ni < 4; ++ni)
                acc[ni] = __builtin_amdgcn_mfma_f32_16x16x32_bf16(
                    af, bq[ni], acc[ni], 0, 0, 0);
        }
#pragma unroll
        for (int ni = 0; ni < 4; ++ni)
#pragma unroll
            for (int r = 0; r < 4; ++r) {
                int col = ni * 16 + lr;
                if (col < NDBL)
                    Db[(wm + lq * 4 + r) * PADD + col] = acc[ni][r];
            }
    }
    __syncthreads();
    // dtc (dt cols 0..7 + C cols 24..39 -> 24 cols) to global
    for (int i = tid; i < CHT * 24; i += 256) {
        int row = i / 24, cc = i - row * 24;
        dtc[(tokBase + row) * 24 + cc] = Db[row * PADD + (cc < 8 ? cc : cc + 16)];
    }

    // --- scan1 + local y (round-0 body, bit-identical) ---
    {
        float w[DTR];
#pragma unroll
        for (int r = 0; r < DTR; ++r) w[r] = dtw[d * DTR + r];
        float bb = dtb[d];
        float dp = Dpv[d];
        float a[DS], q[DS];
        const float4* ap = (const float4*)(Alog + d * DS);
#pragma unroll
        for (int s4 = 0; s4 < 4; ++s4) {
            float4 av = ap[s4];
            a[s4*4+0] = -__expf(av.x); a[s4*4+1] = -__expf(av.y);
            a[s4*4+2] = -__expf(av.z); a[s4*4+3] = -__expf(av.w);
        }
#pragma unroll
        for (int s = 0; s < DS; ++s) q[s] = 0.f;
        float a0 = a[0];
        bool fast = true;
#pragma unroll
        for (int s = 1; s < DS; ++s) {
            float ref = a0 * (float)(s + 1);
            fast = fast && (fabsf(a[s] - ref) <= 1e-5f * fabsf(ref) + 1e-7f);
        }
        float sdt = 0.f;
        bf16_t* yp = ybase + tokBase * DI + d;
        if (fast) {
#pragma unroll 4
            for (int t = 0; t < CHT; ++t) {
                float4 r0 = *(const float4*)&Db[t * PADD + 0];
                float4 r1 = *(const float4*)&Db[t * PADD + 4];
                float xv = bb + r0.x*w[0] + r0.y*w[1] + r0.z*w[2] + r0.w*w[3]
                              + r1.x*w[4] + r1.y*w[5] + r1.z*w[6] + r1.w*w[7];
                float dtv = (xv > 20.f) ? xv : __logf(1.f + __expf(xv));
                sdt += dtv;
                float uv = bf2f(As[t * PADI + d]);
                float dtu = dtv * uv;
                float e1 = __expf(dtv * a0);
                float dA[DS];
                pow_tree(e1, dA);
                float bv[DS], cv[DS];
                *(float4*)&bv[0]  = *(const float4*)&Db[t * PADD + 8];
                *(float4*)&bv[4]  = *(const float4*)&Db[t * PADD + 12];
                *(float4*)&bv[8]  = *(const float4*)&Db[t * PADD + 16];
                *(float4*)&bv[12] = *(const float4*)&Db[t * PADD + 20];
                *(float4*)&cv[0]  = *(const float4*)&Db[t * PADD + 24];
                *(float4*)&cv[4]  = *(const float4*)&Db[t * PADD + 28];
                *(float4*)&cv[8]  = *(const float4*)&Db[t * PADD + 32];
                *(float4*)&cv[12] = *(const float4*)&Db[t * PADD + 36];
                float y0 = 0.f, y1 = 0.f, y2 = 0.f, y3 = 0.f;
#pragma unroll
                for (int s = 0; s < DS; s += 4) {
                    q[s]   = q[s]   * dA[s]   + dtu * bv[s];
                    q[s+1] = q[s+1] * dA[s+1] + dtu * bv[s+1];
                    q[s+2] = q[s+2] * dA[s+2] + dtu * bv[s+2];
                    q[s+3] = q[s+3] * dA[s+3] + dtu * bv[s+3];
                    y0 += q[s]   * cv[s];
                    y1 += q[s+1] * cv[s+1];
                    y2 += q[s+2] * cv[s+2];
                    y3 += q[s+3] * cv[s+3];
                }
                float y = (y0 + y1) + (y2 + y3);
                yp[(size_t)t * DI] = f2bf(y + uv * dp);
            }
        } else {
            for (int t = 0; t < CHT; ++t) {
                float4 r0 = *(const float4*)&Db[t * PADD + 0];
                float4 r1 = *(const float4*)&Db[t * PADD + 4];
                float xv = bb + r0.x*w[0] + r0.y*w[1] + r0.z*w[2] + r0.w*w[3]
                              + r1.x*w[4] + r1.y*w[5] + r1.z*w[6] + r1.w*w[7];
                float dtv = (xv > 20.f) ? xv : __logf(1.f + __expf(xv));
                sdt += dtv;
                float uv = bf2f(As[t * PADI + d]);
                float dtu = dtv * uv;
                float bv[DS], cv[DS];
                *(float4*)&bv[0]  = *(const float4*)&Db[t * PADD + 8];
                *(float4*)&bv[4]  = *(const float4*)&Db[t * PADD + 12];
                *(float4*)&bv[8]  = *(const float4*)&Db[t * PADD + 16];
                *(float4*)&bv[12] = *(const float4*)&Db[t * PADD + 20];
                *(float4*)&cv[0]  = *(const float4*)&Db[t * PADD + 24];
                *(float4*)&cv[4]  = *(const float4*)&Db[t * PADD + 28];
                *(float4*)&cv[8]  = *(const float4*)&Db[t * PADD + 32];
                *(float4*)&cv[12] = *(const float4*)&Db[t * PADD + 36];
                float y = 0.f;
#pragma unroll
                for (int s = 0; s < DS; ++s) {
                    float dA = __expf(dtv * a[s]);
                    q[s] = q[s] * dA + dtu * bv[s];
                    y += q[s] * cv[s];
                }
                yp[(size_t)t * DI] = f2bf(y + uv * dp);
            }
        }
        size_t o = ((size_t)(b * NCH + c) * DI + d) * DS;
#pragma unroll
        for (int s = 0; s < DS; s += 4)
            *(float4*)&Q[o + s] = make_float4(q[s], q[s+1], q[s+2], q[s+3]);
        sdtb[(size_t)(b * NCH + c) * DI + d] = sdt;
    }
}

// ---------------------------------------------------------------------------
// Phase 2: decay from sdt (exact: prod exp(dtv*a) == exp(a*sum dtv)).
// Q[c] overwritten in place with chunk entry state. 16-deep prefetch.
// ---------------------------------------------------------------------------
__global__ __launch_bounds__(128) void k_scan2(float* __restrict__ Q,
                                               const float* __restrict__ sdtb,
                                               const float* __restrict__ Alog) {
    int gid = blockIdx.x * 128 + threadIdx.x;   // Bz*DI*DS threads
    int b = gid >> 12, r = gid & 4095;          // r = d*16 + s
    int d = r >> 4, s = r & 15;
    float a = -__expf(Alog[d * DS + s]);
    const size_t stride = (size_t)DI * DS;
    size_t base = (size_t)b * NCH * stride + r;
    const float* sp = sdtb + (size_t)b * NCH * DI + d;
    float hh = 0.f;
    for (int g = 0; g < NCH / 16; ++g) {
        float qq[16], ee[16];
#pragma unroll
        for (int j = 0; j < 16; ++j)
            qq[j] = Q[base + (size_t)(g * 16 + j) * stride];
#pragma unroll
        for (int j = 0; j < 16; ++j)
            ee[j] = __expf(a * sp[(size_t)(g * 16 + j) * DI]);
#pragma unroll
        for (int j = 0; j < 16; ++j) {
            size_t o = base + (size_t)(g * 16 + j) * stride;
            Q[o] = hh;
            hh = ee[j] * hh + qq[j];
        }
    }
}

// ---------------------------------------------------------------------------
// FUSED: correction + gate -> y tile -> out-GEMM h += y @ out_w^T.
// (pow_tree form kept verbatim — round-0 numerics.)
// ---------------------------------------------------------------------------
__global__ __launch_bounds__(256, 4) void k_corr_out(
        const float* __restrict__ dtc, const bf16_t* __restrict__ ybase,
        const bf16_t* __restrict__ zs,
        const float* __restrict__ dtw, const float* __restrict__ dtb,
        const float* __restrict__ Alog, const float* __restrict__ H0,
        const bf16_t* __restrict__ owb, float* __restrict__ h) {
    __shared__ float epit[CHT * 132];  // 33792 B; aliased as bf16 y tile
    __shared__ float Dt8[CHT * 8];     // 2048 B
    __shared__ float Cs[CHT * DS];     // 4096 B
    bf16_t* yt = (bf16_t*)epit;

    int tid = threadIdx.x;
    size_t tokBase = (size_t)blockIdx.x * CHT;
    int b  = (int)(tokBase >> 13);
    int p0 = (int)(tokBase & (Lz - 1));
    int c  = p0 >> 6;

    for (int i = tid; i < CHT * 24; i += 256) {
        float v = dtc[tokBase * 24 + i];
        int t = i / 24, col = i - t * 24;
        if (col < 8) Dt8[t * 8 + col] = v;
        else         Cs[t * DS + (col - 8)] = v;
    }
    __syncthreads();

    // --- correction + gating (thread = d) ---
    {
        int d = tid;
        float w[DTR];
#pragma unroll
        for (int r = 0; r < DTR; ++r) w[r] = dtw[d * DTR + r];
        float bb = dtb[d];
        float a[DS], gh[DS];
        const float4* ap = (const float4*)(Alog + d * DS);
#pragma unroll
        for (int s4 = 0; s4 < 4; ++s4) {
            float4 av = ap[s4];
            a[s4*4+0] = -__expf(av.x); a[s4*4+1] = -__expf(av.y);
            a[s4*4+2] = -__expf(av.z); a[s4*4+3] = -__expf(av.w);
        }
        size_t ho = ((size_t)(b * NCH + c) * DI + d) * DS;
#pragma unroll
        for (int s = 0; s < DS; s += 4) {
            float4 hv = *(const float4*)&H0[ho + s];
            gh[s] = hv.x; gh[s+1] = hv.y; gh[s+2] = hv.z; gh[s+3] = hv.w;
        }
        float a0 = a[0];
        bool fast = true;
#pragma unroll
        for (int s = 1; s < DS; ++s) {
            float ref = a0 * (float)(s + 1);
            fast = fast && (fabsf(a[s] - ref) <= 1e-5f * fabsf(ref) + 1e-7f);
        }
        const bf16_t* yp = ybase + tokBase * DI + d;
        const bf16_t* zp = zs + tokBase * DI + d;
        float cdt = 0.f;
        float yc[4], zc[4];
#pragma unroll
        for (int j = 0; j < 4; ++j) {
            yc[j] = bf2f(yp[(size_t)j * DI]);
            zc[j] = bf2f(zp[(size_t)j * DI]);
        }
        for (int g = 0; g < CHT / 4; ++g) {
            float yn[4] = {0,0,0,0}, zn[4] = {0,0,0,0};
            if (g + 1 < CHT / 4) {
#pragma unroll
                for (int j = 0; j < 4; ++j) {
                    yn[j] = bf2f(yp[(size_t)((g + 1) * 4 + j) * DI]);
                    zn[j] = bf2f(zp[(size_t)((g + 1) * 4 + j) * DI]);
                }
            }
#pragma unroll
            for (int j = 0; j < 4; ++j) {
                int t = g * 4 + j;
                float4 r0 = *(const float4*)&Dt8[t * 8];
                float4 r1 = *(const float4*)&Dt8[t * 8 + 4];
                float xv = bb + r0.x*w[0] + r0.y*w[1] + r0.z*w[2] + r0.w*w[3]
                              + r1.x*w[4] + r1.y*w[5] + r1.z*w[6] + r1.w*w[7];
                float dtv = (xv > 20.f) ? xv : __logf(1.f + __expf(xv));
                cdt += dtv;
                float cv[DS];
                *(float4*)&cv[0]  = *(const float4*)&Cs[t * DS + 0];
                *(float4*)&cv[4]  = *(const float4*)&Cs[t * DS + 4];
                *(float4*)&cv[8]  = *(const float4*)&Cs[t * DS + 8];
                *(float4*)&cv[12] = *(const float4*)&Cs[t * DS + 12];
                float corr0 = 0.f, corr1 = 0.f, corr2 = 0.f, corr3 = 0.f;
                if (fast) {
                    float e1 = __expf(a0 * cdt);
                    float dA[DS];
                    pow_tree(e1, dA);
#pragma unroll
                    for (int s = 0; s < DS; s += 4) {
                        corr0 += cv[s]   * (gh[s]   * dA[s]);
                        corr1 += cv[s+1] * (gh[s+1] * dA[s+1]);
                        corr2 += cv[s+2] * (gh[s+2] * dA[s+2]);
                        corr3 += cv[s+3] * (gh[s+3] * dA[s+3]);
                    }
                } else {
#pragma unroll
                    for (int s = 0; s < DS; ++s)
                        corr0 += cv[s] * (gh[s] * __expf(a[s] * cdt));
                }
                float y = yc[j] + ((corr0 + corr1) + (corr2 + corr3));
                yt[t * PADI + d] = f2bf(y * zc[j]);
            }
#pragma unroll
            for (int j = 0; j < 4; ++j) { yc[j] = yn[j]; zc[j] = zn[j]; }
        }
    }
    __syncthreads();

    // --- out-GEMM: h[64 x 128] += y[64 x 256] @ out_w^T ---
    int wave = tid >> 6, lane = tid & 63;
    int lr = lane & 15, lq = lane >> 4;
    int wm = wave * 16;
    f4 zf = {0.f, 0.f, 0.f, 0.f};
    f4 acc[8];
#pragma unroll
    for (int ni = 0; ni < 8; ++ni) acc[ni] = zf;
    const bf16_t* Bp = owb + (size_t)lr * DI + lq * 8;
#pragma unroll
    for (int kk = 0; kk < DI; kk += 32) {
        bf8 af = *(const bf8*)&yt[(wm + lr) * PADI + lq * 8 + kk];
        bf8 bq[8];
#pragma unroll
        for (int ni = 0; ni < 8; ++ni)
            bq[ni] = *(const bf8*)(Bp + (size_t)ni * 16 * DI + kk);
#pragma unroll
        for (int ni = 0; ni < 8; ++ni)
            acc[ni] = __builtin_amdgcn_mfma_f32_16x16x32_bf16(
                af, bq[ni], acc[ni], 0, 0, 0);
    }
    __syncthreads();   // yt reads done; epit may be overwritten
#pragma unroll
    for (int ni = 0; ni < 8; ++ni)
#pragma unroll
        for (int r = 0; r < 4; ++r)
            epit[(wm + lq * 4 + r) * 132 + ni * 16 + lr] = acc[ni][r];
    __syncthreads();
    for (int i = tid; i < 2048; i += 256) {
        int row = i >> 5, col = (i & 31) * 4;
        float4 v = *(const float4*)&epit[row * 132 + col];
        float4 old = *(const float4*)&h[(tokBase + row) * DM + col];
        old.x += v.x; old.y += v.y; old.z += v.z; old.w += v.w;
        *(float4*)&h[(tokBase + row) * DM + col] = old;
    }
}

// ---------------------------------------------------------------------------
__global__ __launch_bounds__(256) void k_final(float* __restrict__ h,
                                               const float* __restrict__ w,
                                               const float* __restrict__ bias,
                                               float* __restrict__ hg) {
    __shared__ float sbuf[DM];
    int t    = blockIdx.x * 16 + (threadIdx.x >> 4);
    int lane = threadIdx.x & 15;
    int b    = t >> 13;
    if (threadIdx.x < DM) sbuf[threadIdx.x] = 0.f;
    __syncthreads();
    float4* hp = (float4*)(h + (size_t)t * DM + lane * 8);
    float4 v0 = hp[0], v1 = hp[1];
    float s = v0.x + v0.y + v0.z + v0.w + v1.x + v1.y + v1.z + v1.w;
    float q = v0.x*v0.x + v0.y*v0.y + v0.z*v0.z + v0.w*v0.w +
              v1.x*v1.x + v1.y*v1.y + v1.z*v1.z + v1.w*v1.w;
#pragma unroll
    for (int off = 1; off < 16; off <<= 1) {
        s += __shfl_xor(s, off);
        q += __shfl_xor(q, off);
    }
    float mean = s * (1.f / DM);
    float var  = q * (1.f / DM) - mean * mean;
    float rstd = rsqrtf(var + 1e-5f);
    const float4* wp = (const float4*)(w + lane * 8);
    const float4* bp = (const float4*)(bias + lane * 8);
    float4 w0 = wp[0], w1 = wp[1], b0 = bp[0], b1 = bp[1];
    float4 o0, o1;
    o0.x = (v0.x - mean) * rstd * w0.x + b0.x;
    o0.y = (v0.y - mean) * rstd * w0.y + b0.y;
    o0.z = (v0.z - mean) * rstd * w0.z + b0.z;
    o0.w = (v0.w - mean) * rstd * w0.w + b0.w;
    o1.x = (v1.x - mean) * rstd * w1.x + b1.x;
    o1.y = (v1.y - mean) * rstd * w1.y + b1.y;
    o1.z = (v1.z - mean) * rstd * w1.z + b1.z;
    o1.w = (v1.w - mean) * rstd * w1.w + b1.w;
    hp[0] = o0; hp[1] = o1;
    int dbase = lane * 8;
    atomicAdd(&sbuf[dbase + 0], o0.x); atomicAdd(&sbuf[dbase + 1], o0.y);
    atomicAdd(&sbuf[dbase + 2], o0.z); atomicAdd(&sbuf[dbase + 3], o0.w);
    atomicAdd(&sbuf[dbase + 4], o1.x); atomicAdd(&sbuf[dbase + 5], o1.y);
    atomicAdd(&sbuf[dbase + 6], o1.z); atomicAdd(&sbuf[dbase + 7], o1.w);
    __syncthreads();
    if (threadIdx.x < DM)
        atomicAdd(&hg[b * DM + threadIdx.x], sbuf[threadIdx.x] * (1.f / Lz));
}

// ---------------------------------------------------------------------------
extern "C" void kernel_launch(void* const* d_in, const int* in_sizes, int n_in,
                              void* d_out, int out_size, void* d_ws, size_t ws_size,
                              hipStream_t stream) {
    const float* x       = (const float*)d_in[0];
    const float* proj_w  = (const float*)d_in[1];
    const float* proj_b  = (const float*)d_in[2];
    const float* ln_w    = (const float*)d_in[3];
    const float* ln_b    = (const float*)d_in[4];
    const float* in_w    = (const float*)d_in[5];
    const float* conv_w  = (const float*)d_in[6];
    const float* conv_b  = (const float*)d_in[7];
    const float* xproj_w = (const float*)d_in[8];
    const float* dt_w    = (const float*)d_in[9];
    const float* dt_b    = (const float*)d_in[10];
    const float* A_log   = (const float*)d_in[11];
    const float* Dp      = (const float*)d_in[12];
    const float* out_w   = (const float*)d_in[13];
    const float* lnout_w = (const float*)d_in[14];
    const float* lnout_b = (const float*)d_in[15];

    float* out = (float*)d_out;
    float* h   = out;                        // [BL][128] lives in d_out
    float* hg  = out + (size_t)BLz * DM;     // [B][128]

    // Workspace layout (u_pre slot now unused — kept for layout stability).
    char* ws = (char*)d_ws;
    bf16_t* zs    = (bf16_t*)(ws + 33554432ULL);      // 32 MiB
    bf16_t* ybase = (bf16_t*)(ws + 67108864ULL);      // 32 MiB
    float*  dtc   = (float*) (ws + 100663296ULL);     // 6 MiB  (BL*24*4)
    float*  Q     = (float*) (ws + 106954752ULL);     // 16 MiB
    float*  sdtb  = (float*) (ws + 123731968ULL);     // 1 MiB
    bf16_t* inwb  = (bf16_t*)(ws + 124780544ULL);     // 512 KiB
    bf16_t* owb   = (bf16_t*)(ws + 125304832ULL);     // 256 KiB
    bf16_t* xwb   = (bf16_t*)(ws + 125566976ULL);     // 128 KiB

    k_wconv<<<1024, 256, 0, stream>>>(in_w, out_w, xproj_w, inwb, owb, xwb, hg);
    k_inproj<<<BLz / 2, 256, 0, stream>>>(x, proj_w, proj_b, h);

    for (int i = 0; i < DEPTHN; ++i) {
        k_lnscan<<<BLz / CHT, 256, 0, stream>>>(
            h, ln_w + i * DM, ln_b + i * DM,
            inwb + (size_t)i * 512 * DM, xwb + (size_t)i * 64 * DI,
            conv_w + i * DI * 4, conv_b + i * DI,
            dt_w + i * DI * DTR, dt_b + i * DI, A_log + i * DI * DS,
            Dp + i * DI, zs, dtc, Q, sdtb, ybase);
        k_scan2<<<(Bz * DI * DS) / 128, 128, 0, stream>>>(
            Q, sdtb, A_log + i * DI * DS);
        k_corr_out<<<BLz / CHT, 256, 0, stream>>>(
            dtc, ybase, zs,
            dt_w + i * DI * DTR, dt_b + i * DI,
            A_log + i * DI * DS, Q,
            owb + (size_t)i * DM * DI, h);
    }

    k_final<<<BLz / 16, 256, 0, stream>>>(h, lnout_w, lnout_b, hg);
}

// Round 5
// 867.898 us; speedup vs baseline: 1.1899x; 1.0164x over previous
//
#include <hip/hip_runtime.h>
#include <hip/hip_bf16.h>
#include <math.h>

// Problem constants (MambaEncoder)
#define Bz     8
#define Lz     8192
#define DM     128      // d_model
#define DI     256      // d_inner
#define DS     16       // d_state
#define DTR    8        // dt_rank
#define NDBL   40       // DTR + 2*DS
#define DEPTHN 4
#define BLz    (Bz*Lz)  // 65536 tokens
#define CHT    64       // scan chunk length == M-tile
#define NCH    (Lz/CHT) // 128 chunks per sequence
#define PADI   264      // bf16 tile row stride
#define PADD   44       // f32 Db row stride

typedef unsigned short bf16_t;
typedef __attribute__((ext_vector_type(8))) __bf16 bf8;
typedef __attribute__((ext_vector_type(4))) float f4;
typedef __attribute__((ext_vector_type(8))) unsigned short us8;

__device__ __forceinline__ float bf2f(bf16_t u) {
    return __uint_as_float(((unsigned)u) << 16);
}
__device__ __forceinline__ bf16_t f2bf(float f) {
    unsigned u = __float_as_uint(f);
    u = u + 0x7FFFu + ((u >> 16) & 1u);   // round-to-nearest-even
    return (bf16_t)(u >> 16);
}
__device__ __forceinline__ float fast_rcp(float x) {
    return __builtin_amdgcn_rcpf(x);
}

// dA power tree: dA[s] = e1^(s+1), depth 4.
__device__ __forceinline__ void pow_tree(float e1, float dA[DS]) {
    float e2 = e1 * e1, e3 = e2 * e1, e4 = e2 * e2;
    float e8 = e4 * e4;
    dA[0] = e1;       dA[1] = e2;       dA[2] = e3;       dA[3] = e4;
    dA[4] = e4 * e1;  dA[5] = e4 * e2;  dA[6] = e4 * e3;  dA[7] = e8;
    dA[8] = e8 * e1;  dA[9] = e8 * e2;  dA[10] = e8 * e3; dA[11] = e8 * e4;
    dA[12] = e8 * dA[4]; dA[13] = e8 * dA[5]; dA[14] = e8 * dA[6];
    dA[15] = e8 * e8;
}

// ---------------------------------------------------------------------------
// Convert weights fp32 -> bf16 (xproj padded 40->64 rows) + zero hg.
// ---------------------------------------------------------------------------
__global__ __launch_bounds__(256) void k_wconv(const float* __restrict__ inw,
                                               const float* __restrict__ ow,
                                               const float* __restrict__ xw,
                                               bf16_t* __restrict__ inwb,
                                               bf16_t* __restrict__ owb,
                                               bf16_t* __restrict__ xwb,
                                               float* __restrict__ hg) {
    int i = blockIdx.x * 256 + threadIdx.x;
    if (i < Bz * DM) hg[i] = 0.f;
    if (i < DEPTHN * 512 * DM) inwb[i] = f2bf(inw[i]);
    if (i < DEPTHN * DM * DI)  owb[i]  = f2bf(ow[i]);
    if (i < DEPTHN * 64 * DI) {
        int layer = i >> 14, rk = i & 16383, r = rk >> 8, k = rk & 255;
        xwb[i] = (r < NDBL) ? f2bf(xw[((size_t)layer * NDBL + r) * DI + k]) : (bf16_t)0;
    }
}

// ---------------------------------------------------------------------------
__global__ __launch_bounds__(256) void k_inproj(const float* __restrict__ x,
                                                const float* __restrict__ pw,
                                                const float* __restrict__ pb,
                                                float* __restrict__ h) {
    int t = blockIdx.x * 2 + (threadIdx.x >> 7);
    int d = threadIdx.x & 127;
    int b = t >> 13, l = t & (Lz - 1);
    float acc = pb[d];
#pragma unroll
    for (int c = 0; c < 3; ++c)
        acc += x[(size_t)(b * 3 + c) * Lz + l] * pw[d * 3 + c];
    h[(size_t)t * DM + d] = acc;
}

// ---------------------------------------------------------------------------
// FUSED per-64-token chunk: LayerNorm (64+3 halo rows) -> in-proj GEMM
// (u -> As LDS; halo via extra MFMA m-tile @row51, bit-identical) ->
// z silu stored DIRECT to zs (no LDS staging) -> conv+SiLU (own-wave
// columns, pre-barrier) -> xproj GEMM -> scan1.  3 barriers total
// (was 9).  All numerics bit-identical to round-4.
// LDS: As 33792 + Rb 18496 = 52288 B -> 3 blocks/CU.
// ---------------------------------------------------------------------------
__global__ __launch_bounds__(256, 3) void k_lnscan(
        const float* __restrict__ h,
        const float* __restrict__ lw, const float* __restrict__ lb,
        const bf16_t* __restrict__ inwb, const bf16_t* __restrict__ xwb,
        const float* __restrict__ cw, const float* __restrict__ cb,
        const float* __restrict__ dtw, const float* __restrict__ dtb,
        const float* __restrict__ Alog, const float* __restrict__ Dpv,
        bf16_t* __restrict__ zs, float* __restrict__ dtc,
        float* __restrict__ Q, float* __restrict__ sdtb,
        bf16_t* __restrict__ ybase) {
    __shared__ bf16_t As[CHT * PADI];   // 33792 B: u tile (conv'd in place)
    __shared__ char   Rb[18496];        // xs(67x136 bf16) -> Db(64x44 f32)
    bf16_t* xs = (bf16_t*)Rb;
    float*  Db = (float*)Rb;

    int tid = threadIdx.x;
    size_t tokBase = (size_t)blockIdx.x * CHT;
    int b  = (int)(tokBase >> 13);
    int p0 = (int)(tokBase & (Lz - 1));
    int c  = p0 >> 6;
    int d  = tid;

    // --- P0: LayerNorm 64 chunk rows + 3 halo rows (xs rows 64..66) ---
#pragma unroll
    for (int p = 0; p < 5; ++p) {
        int row = p * 16 + (tid >> 4);
        if (row >= 67) continue;                 // whole 16-lane groups skip
        int lane = tid & 15;
        if (row >= 64 && p0 == 0) {              // no halo at seq start: zero
            ushort4 z4 = {0, 0, 0, 0};
            *(ushort4*)&xs[row * 136 + lane * 8]     = z4;
            *(ushort4*)&xs[row * 136 + lane * 8 + 4] = z4;
            continue;
        }
        size_t tok = (row < 64) ? (tokBase + row) : (tokBase - 3 + (row - 64));
        const float4* hp = (const float4*)(h + tok * DM + lane * 8);
        float4 v0 = hp[0], v1 = hp[1];
        float s = v0.x + v0.y + v0.z + v0.w + v1.x + v1.y + v1.z + v1.w;
        float q = v0.x*v0.x + v0.y*v0.y + v0.z*v0.z + v0.w*v0.w +
                  v1.x*v1.x + v1.y*v1.y + v1.z*v1.z + v1.w*v1.w;
#pragma unroll
        for (int off = 1; off < 16; off <<= 1) {
            s += __shfl_xor(s, off);
            q += __shfl_xor(q, off);
        }
        float mean = s * (1.f / DM);
        float var  = q * (1.f / DM) - mean * mean;
        float rstd = rsqrtf(var + 1e-5f);
        const float4* wp = (const float4*)(lw + lane * 8);
        const float4* bp = (const float4*)(lb + lane * 8);
        float4 w0 = wp[0], w1 = wp[1], b0 = bp[0], b1 = bp[1];
        ushort4 o0, o1;
        o0.x = f2bf((v0.x - mean) * rstd * w0.x + b0.x);
        o0.y = f2bf((v0.y - mean) * rstd * w0.y + b0.y);
        o0.z = f2bf((v0.z - mean) * rstd * w0.z + b0.z);
        o0.w = f2bf((v0.w - mean) * rstd * w0.w + b0.w);
        o1.x = f2bf((v1.x - mean) * rstd * w1.x + b1.x);
        o1.y = f2bf((v1.y - mean) * rstd * w1.y + b1.y);
        o1.z = f2bf((v1.z - mean) * rstd * w1.z + b1.z);
        o1.w = f2bf((v1.w - mean) * rstd * w1.w + b1.w);
        *(ushort4*)&xs[row * 136 + lane * 8]     = o0;
        *(ushort4*)&xs[row * 136 + lane * 8 + 4] = o1;
    }
    __syncthreads();   // (barrier 1) xs ready

    int wave = tid >> 6, lane = tid & 63;
    int lr = lane & 15, lq = lane >> 4;
    f4 zf = {0.f, 0.f, 0.f, 0.f};

    // --- P1: u-GEMM (cols 0..255, wave n-slice 64) -> As directly;
    //     fused halo m-tile (A rows 51+lr -> C rows 51..66, keep 64..66) ---
    float uh3 = 0.f, uh2 = 0.f, uh1 = 0.f;
    {
        int wn = wave * 64;
        f4 accu[4][4];
        f4 accH[4];
#pragma unroll
        for (int mi = 0; mi < 4; ++mi)
#pragma unroll
            for (int ni = 0; ni < 4; ++ni) accu[mi][ni] = zf;
#pragma unroll
        for (int ni = 0; ni < 4; ++ni) accH[ni] = zf;
        const bf16_t* Bp = inwb + (size_t)(wn + lr) * DM + lq * 8;
#pragma unroll
        for (int kk = 0; kk < DM; kk += 32) {
            bf8 af[4], afh, bq[4];
#pragma unroll
            for (int mi = 0; mi < 4; ++mi)
                af[mi] = *(const bf8*)&xs[(mi * 16 + lr) * 136 + lq * 8 + kk];
            afh = *(const bf8*)&xs[(51 + lr) * 136 + lq * 8 + kk];
#pragma unroll
            for (int ni = 0; ni < 4; ++ni)
                bq[ni] = *(const bf8*)(Bp + (size_t)ni * 16 * DM + kk);
#pragma unroll
            for (int mi = 0; mi < 4; ++mi)
#pragma unroll
                for (int ni = 0; ni < 4; ++ni)
                    accu[mi][ni] = __builtin_amdgcn_mfma_f32_16x16x32_bf16(
                        af[mi], bq[ni], accu[mi][ni], 0, 0, 0);
#pragma unroll
            for (int ni = 0; ni < 4; ++ni)
                accH[ni] = __builtin_amdgcn_mfma_f32_16x16x32_bf16(
                    afh, bq[ni], accH[ni], 0, 0, 0);
        }
#pragma unroll
        for (int mi = 0; mi < 4; ++mi)
#pragma unroll
            for (int ni = 0; ni < 4; ++ni)
#pragma unroll
                for (int r = 0; r < 4; ++r)
                    As[(mi * 16 + lq * 4 + r) * PADI + wn + ni * 16 + lr] =
                        f2bf(accu[mi][ni][r]);

        // halo rows 64..66 = (lq=3, r=1..3), lanes 48+lr hold col wn+ni*16+lr.
        if (p0 != 0) {
            int src   = 48 + (d & 15);
            int nisel = (d >> 4) & 3;
            float hv[3];
#pragma unroll
            for (int j = 0; j < 3; ++j) {
                float v0 = __shfl(bf2f(f2bf(accH[0][j + 1])), src);
                float v1 = __shfl(bf2f(f2bf(accH[1][j + 1])), src);
                float v2 = __shfl(bf2f(f2bf(accH[2][j + 1])), src);
                float v3 = __shfl(bf2f(f2bf(accH[3][j + 1])), src);
                hv[j] = (nisel == 0) ? v0 : (nisel == 1) ? v1
                      : (nisel == 2) ? v2 : v3;
            }
            uh3 = hv[0]; uh2 = hv[1]; uh1 = hv[2];
        }
    }

    // --- P2: z-GEMM (cols 256..511) -> silu -> DIRECT zs stores ---
    {
        int wnz = 256 + wave * 64;
        f4 accz[4][4];
#pragma unroll
        for (int mi = 0; mi < 4; ++mi)
#pragma unroll
            for (int ni = 0; ni < 4; ++ni) accz[mi][ni] = zf;
        const bf16_t* Bp = inwb + (size_t)(wnz + lr) * DM + lq * 8;
#pragma unroll
        for (int kk = 0; kk < DM; kk += 32) {
            bf8 af[4], bq[4];
#pragma unroll
            for (int mi = 0; mi < 4; ++mi)
                af[mi] = *(const bf8*)&xs[(mi * 16 + lr) * 136 + lq * 8 + kk];
#pragma unroll
            for (int ni = 0; ni < 4; ++ni)
                bq[ni] = *(const bf8*)(Bp + (size_t)ni * 16 * DM + kk);
#pragma unroll
            for (int mi = 0; mi < 4; ++mi)
#pragma unroll
                for (int ni = 0; ni < 4; ++ni)
                    accz[mi][ni] = __builtin_amdgcn_mfma_f32_16x16x32_bf16(
                        af[mi], bq[ni], accz[mi][ni], 0, 0, 0);
        }
        // direct scalar stores (same values/addresses as staged path)
#pragma unroll
        for (int mi = 0; mi < 4; ++mi)
#pragma unroll
            for (int ni = 0; ni < 4; ++ni)
#pragma unroll
                for (int r = 0; r < 4; ++r) {
                    float v = accz[mi][ni][r];
                    float sil = v * fast_rcp(1.f + __expf(-v));
                    zs[(tokBase + mi * 16 + lq * 4 + r) * DI
                       + wave * 64 + ni * 16 + lr] = f2bf(sil);
                }
    }

    // --- conv(k=4)+SiLU in place: column d was written by THIS wave in P1
    //     (wave w owns As cols [64w,64w+64)); same-wave LDS RAW is ordered,
    //     so no barrier needed before conv. ---
    {
        float cw0 = cw[d*4+0], cw1 = cw[d*4+1], cw2 = cw[d*4+2], cw3 = cw[d*4+3];
        float cbb = cb[d];
        float x3 = uh3, x2 = uh2, x1 = uh1;
#pragma unroll 8
        for (int t = 0; t < CHT; ++t) {
            float x0 = bf2f(As[t * PADI + d]);
            float conv = cbb + cw0*x3 + cw1*x2 + cw2*x1 + cw3*x0;
            float sil = conv * fast_rcp(1.f + __expf(-conv));
            As[t * PADI + d] = f2bf(sil);
            x3 = x2; x2 = x1; x1 = x0;
        }
    }
    __syncthreads();   // (barrier 2) As sil complete all waves; xs dead

    // --- xproj GEMM: Db[64 x 40] = u @ xw^T (overwrites xs region) ---
    {
        int wm = wave * 16;
        f4 acc[4];
#pragma unroll
        for (int ni = 0; ni < 4; ++ni) acc[ni] = zf;
        const bf16_t* Bp = xwb + (size_t)lr * DI + lq * 8;
#pragma unroll
        for (int kk = 0; kk < DI; kk += 32) {
            bf8 af = *(const bf8*)&As[(wm + lr) * PADI + lq * 8 + kk];
            bf8 bq[4];
#pragma unroll
            for (int ni = 0; ni < 4; ++ni)
                bq[ni] = *(const bf8*)(Bp + (size_t)ni * 16 * DI + kk);
#pragma unroll
            for (int ni = 0; ni < 4; ++ni)
                acc[ni] = __builtin_amdgcn_mfma_f32_16x16x32_bf16(
                    af, bq[ni], acc[ni], 0, 0, 0);
        }
#pragma unroll
        for (int ni = 0; ni < 4; ++ni)
#pragma unroll
            for (int r = 0; r < 4; ++r) {
                int col = ni * 16 + lr;
                if (col < NDBL)
                    Db[(wm + lq * 4 + r) * PADD + col] = acc[ni][r];
            }
    }
    __syncthreads();   // (barrier 3) Db ready
    // dtc (dt cols 0..7 + C cols 24..39 -> 24 cols) to global
    for (int i = tid; i < CHT * 24; i += 256) {
        int row = i / 24, cc = i - row * 24;
        dtc[(tokBase + row) * 24 + cc] = Db[row * PADD + (cc < 8 ? cc : cc + 16)];
    }

    // --- scan1 + local y (round-0 body, bit-identical) ---
    {
        float w[DTR];
#pragma unroll
        for (int r = 0; r < DTR; ++r) w[r] = dtw[d * DTR + r];
        float bb = dtb[d];
        float dp = Dpv[d];
        float a[DS], q[DS];
        const float4* ap = (const float4*)(Alog + d * DS);
#pragma unroll
        for (int s4 = 0; s4 < 4; ++s4) {
            float4 av = ap[s4];
            a[s4*4+0] = -__expf(av.x); a[s4*4+1] = -__expf(av.y);
            a[s4*4+2] = -__expf(av.z); a[s4*4+3] = -__expf(av.w);
        }
#pragma unroll
        for (int s = 0; s < DS; ++s) q[s] = 0.f;
        float a0 = a[0];
        bool fast = true;
#pragma unroll
        for (int s = 1; s < DS; ++s) {
            float ref = a0 * (float)(s + 1);
            fast = fast && (fabsf(a[s] - ref) <= 1e-5f * fabsf(ref) + 1e-7f);
        }
        float sdt = 0.f;
        bf16_t* yp = ybase + tokBase * DI + d;
        if (fast) {
#pragma unroll 4
            for (int t = 0; t < CHT; ++t) {
                float4 r0 = *(const float4*)&Db[t * PADD + 0];
                float4 r1 = *(const float4*)&Db[t * PADD + 4];
                float xv = bb + r0.x*w[0] + r0.y*w[1] + r0.z*w[2] + r0.w*w[3]
                              + r1.x*w[4] + r1.y*w[5] + r1.z*w[6] + r1.w*w[7];
                float dtv = (xv > 20.f) ? xv : __logf(1.f + __expf(xv));
                sdt += dtv;
                float uv = bf2f(As[t * PADI + d]);
                float dtu = dtv * uv;
                float e1 = __expf(dtv * a0);
                float dA[DS];
                pow_tree(e1, dA);
                float bv[DS], cv[DS];
                *(float4*)&bv[0]  = *(const float4*)&Db[t * PADD + 8];
                *(float4*)&bv[4]  = *(const float4*)&Db[t * PADD + 12];
                *(float4*)&bv[8]  = *(const float4*)&Db[t * PADD + 16];
                *(float4*)&bv[12] = *(const float4*)&Db[t * PADD + 20];
                *(float4*)&cv[0]  = *(const float4*)&Db[t * PADD + 24];
                *(float4*)&cv[4]  = *(const float4*)&Db[t * PADD + 28];
                *(float4*)&cv[8]  = *(const float4*)&Db[t * PADD + 32];
                *(float4*)&cv[12] = *(const float4*)&Db[t * PADD + 36];
                float y0 = 0.f, y1 = 0.f, y2 = 0.f, y3 = 0.f;
#pragma unroll
                for (int s = 0; s < DS; s += 4) {
                    q[s]   = q[s]   * dA[s]   + dtu * bv[s];
                    q[s+1] = q[s+1] * dA[s+1] + dtu * bv[s+1];
                    q[s+2] = q[s+2] * dA[s+2] + dtu * bv[s+2];
                    q[s+3] = q[s+3] * dA[s+3] + dtu * bv[s+3];
                    y0 += q[s]   * cv[s];
                    y1 += q[s+1] * cv[s+1];
                    y2 += q[s+2] * cv[s+2];
                    y3 += q[s+3] * cv[s+3];
                }
                float y = (y0 + y1) + (y2 + y3);
                yp[(size_t)t * DI] = f2bf(y + uv * dp);
            }
        } else {
            for (int t = 0; t < CHT; ++t) {
                float4 r0 = *(const float4*)&Db[t * PADD + 0];
                float4 r1 = *(const float4*)&Db[t * PADD + 4];
                float xv = bb + r0.x*w[0] + r0.y*w[1] + r0.z*w[2] + r0.w*w[3]
                              + r1.x*w[4] + r1.y*w[5] + r1.z*w[6] + r1.w*w[7];
                float dtv = (xv > 20.f) ? xv : __logf(1.f + __expf(xv));
                sdt += dtv;
                float uv = bf2f(As[t * PADI + d]);
                float dtu = dtv * uv;
                float bv[DS], cv[DS];
                *(float4*)&bv[0]  = *(const float4*)&Db[t * PADD + 8];
                *(float4*)&bv[4]  = *(const float4*)&Db[t * PADD + 12];
                *(float4*)&bv[8]  = *(const float4*)&Db[t * PADD + 16];
                *(float4*)&bv[12] = *(const float4*)&Db[t * PADD + 20];
                *(float4*)&cv[0]  = *(const float4*)&Db[t * PADD + 24];
                *(float4*)&cv[4]  = *(const float4*)&Db[t * PADD + 28];
                *(float4*)&cv[8]  = *(const float4*)&Db[t * PADD + 32];
                *(float4*)&cv[12] = *(const float4*)&Db[t * PADD + 36];
                float y = 0.f;
#pragma unroll
                for (int s = 0; s < DS; ++s) {
                    float dA = __expf(dtv * a[s]);
                    q[s] = q[s] * dA + dtu * bv[s];
                    y += q[s] * cv[s];
                }
                yp[(size_t)t * DI] = f2bf(y + uv * dp);
            }
        }
        size_t o = ((size_t)(b * NCH + c) * DI + d) * DS;
#pragma unroll
        for (int s = 0; s < DS; s += 4)
            *(float4*)&Q[o + s] = make_float4(q[s], q[s+1], q[s+2], q[s+3]);
        sdtb[(size_t)(b * NCH + c) * DI + d] = sdt;
    }
}

// ---------------------------------------------------------------------------
// Phase 2: decay from sdt (exact: prod exp(dtv*a) == exp(a*sum dtv)).
// Q[c] overwritten in place with chunk entry state. Double-buffered 16-deep
// prefetch (group g+1 loads issued before group g compute; loads precede
// stores in program order, element g+1 never overwritten before its load).
// ---------------------------------------------------------------------------
__global__ __launch_bounds__(128) void k_scan2(float* __restrict__ Q,
                                               const float* __restrict__ sdtb,
                                               const float* __restrict__ Alog) {
    int gid = blockIdx.x * 128 + threadIdx.x;   // Bz*DI*DS threads
    int b = gid >> 12, r = gid & 4095;          // r = d*16 + s
    int d = r >> 4, s = r & 15;
    float a = -__expf(Alog[d * DS + s]);
    const size_t stride = (size_t)DI * DS;
    size_t base = (size_t)b * NCH * stride + r;
    const float* sp = sdtb + (size_t)b * NCH * DI + d;
    float hh = 0.f;
    float qq[16], sv[16];
#pragma unroll
    for (int j = 0; j < 16; ++j) {
        qq[j] = Q[base + (size_t)j * stride];
        sv[j] = sp[(size_t)j * DI];
    }
    for (int g = 0; g < NCH / 16; ++g) {
        float qn[16], sn[16];
        if (g + 1 < NCH / 16) {
#pragma unroll
            for (int j = 0; j < 16; ++j) {
                qn[j] = Q[base + (size_t)((g + 1) * 16 + j) * stride];
                sn[j] = sp[(size_t)((g + 1) * 16 + j) * DI];
            }
        }
        float ee[16];
#pragma unroll
        for (int j = 0; j < 16; ++j)
            ee[j] = __expf(a * sv[j]);
#pragma unroll
        for (int j = 0; j < 16; ++j) {
            size_t o = base + (size_t)(g * 16 + j) * stride;
            Q[o] = hh;
            hh = ee[j] * hh + qq[j];
        }
        if (g + 1 < NCH / 16) {
#pragma unroll
            for (int j = 0; j < 16; ++j) { qq[j] = qn[j]; sv[j] = sn[j]; }
        }
    }
}

// ---------------------------------------------------------------------------
// FUSED: correction + gate -> y tile -> out-GEMM h += y @ out_w^T.
// (pow_tree form kept verbatim — round-0 numerics.)
// ---------------------------------------------------------------------------
__global__ __launch_bounds__(256, 4) void k_corr_out(
        const float* __restrict__ dtc, const bf16_t* __restrict__ ybase,
        const bf16_t* __restrict__ zs,
        const float* __restrict__ dtw, const float* __restrict__ dtb,
        const float* __restrict__ Alog, const float* __restrict__ H0,
        const bf16_t* __restrict__ owb, float* __restrict__ h) {
    __shared__ float epit[CHT * 132];  // 33792 B; aliased as bf16 y tile
    __shared__ float Dt8[CHT * 8];     // 2048 B
    __shared__ float Cs[CHT * DS];     // 4096 B
    bf16_t* yt = (bf16_t*)epit;

    int tid = threadIdx.x;
    size_t tokBase = (size_t)blockIdx.x * CHT;
    int b  = (int)(tokBase >> 13);
    int p0 = (int)(tokBase & (Lz - 1));
    int c  = p0 >> 6;

    for (int i = tid; i < CHT * 24; i += 256) {
        float v = dtc[tokBase * 24 + i];
        int t = i / 24, col = i - t * 24;
        if (col < 8) Dt8[t * 8 + col] = v;
        else         Cs[t * DS + (col - 8)] = v;
    }
    __syncthreads();

    // --- correction + gating (thread = d) ---
    {
        int d = tid;
        float w[DTR];
#pragma unroll
        for (int r = 0; r < DTR; ++r) w[r] = dtw[d * DTR + r];
        float bb = dtb[d];
        float a[DS], gh[DS];
        const float4* ap = (const float4*)(Alog + d * DS);
#pragma unroll
        for (int s4 = 0; s4 < 4; ++s4) {
            float4 av = ap[s4];
            a[s4*4+0] = -__expf(av.x); a[s4*4+1] = -__expf(av.y);
            a[s4*4+2] = -__expf(av.z); a[s4*4+3] = -__expf(av.w);
        }
        size_t ho = ((size_t)(b * NCH + c) * DI + d) * DS;
#pragma unroll
        for (int s = 0; s < DS; s += 4) {
            float4 hv = *(const float4*)&H0[ho + s];
            gh[s] = hv.x; gh[s+1] = hv.y; gh[s+2] = hv.z; gh[s+3] = hv.w;
        }
        float a0 = a[0];
        bool fast = true;
#pragma unroll
        for (int s = 1; s < DS; ++s) {
            float ref = a0 * (float)(s + 1);
            fast = fast && (fabsf(a[s] - ref) <= 1e-5f * fabsf(ref) + 1e-7f);
        }
        const bf16_t* yp = ybase + tokBase * DI + d;
        const bf16_t* zp = zs + tokBase * DI + d;
        float cdt = 0.f;
        float yc[4], zc[4];
#pragma unroll
        for (int j = 0; j < 4; ++j) {
            yc[j] = bf2f(yp[(size_t)j * DI]);
            zc[j] = bf2f(zp[(size_t)j * DI]);
        }
        for (int g = 0; g < CHT / 4; ++g) {
            float yn[4] = {0,0,0,0}, zn[4] = {0,0,0,0};
            if (g + 1 < CHT / 4) {
#pragma unroll
                for (int j = 0; j < 4; ++j) {
                    yn[j] = bf2f(yp[(size_t)((g + 1) * 4 + j) * DI]);
                    zn[j] = bf2f(zp[(size_t)((g + 1) * 4 + j) * DI]);
                }
            }
#pragma unroll
            for (int j = 0; j < 4; ++j) {
                int t = g * 4 + j;
                float4 r0 = *(const float4*)&Dt8[t * 8];
                float4 r1 = *(const float4*)&Dt8[t * 8 + 4];
                float xv = bb + r0.x*w[0] + r0.y*w[1] + r0.z*w[2] + r0.w*w[3]
                              + r1.x*w[4] + r1.y*w[5] + r1.z*w[6] + r1.w*w[7];
                float dtv = (xv > 20.f) ? xv : __logf(1.f + __expf(xv));
                cdt += dtv;
                float cv[DS];
                *(float4*)&cv[0]  = *(const float4*)&Cs[t * DS + 0];
                *(float4*)&cv[4]  = *(const float4*)&Cs[t * DS + 4];
                *(float4*)&cv[8]  = *(const float4*)&Cs[t * DS + 8];
                *(float4*)&cv[12] = *(const float4*)&Cs[t * DS + 12];
                float corr0 = 0.f, corr1 = 0.f, corr2 = 0.f, corr3 = 0.f;
                if (fast) {
                    float e1 = __expf(a0 * cdt);
                    float dA[DS];
                    pow_tree(e1, dA);
#pragma unroll
                    for (int s = 0; s < DS; s += 4) {
                        corr0 += cv[s]   * (gh[s]   * dA[s]);
                        corr1 += cv[s+1] * (gh[s+1] * dA[s+1]);
                        corr2 += cv[s+2] * (gh[s+2] * dA[s+2]);
                        corr3 += cv[s+3] * (gh[s+3] * dA[s+3]);
                    }
                } else {
#pragma unroll
                    for (int s = 0; s < DS; ++s)
                        corr0 += cv[s] * (gh[s] * __expf(a[s] * cdt));
                }
                float y = yc[j] + ((corr0 + corr1) + (corr2 + corr3));
                yt[t * PADI + d] = f2bf(y * zc[j]);
            }
#pragma unroll
            for (int j = 0; j < 4; ++j) { yc[j] = yn[j]; zc[j] = zn[j]; }
        }
    }
    __syncthreads();

    // --- out-GEMM: h[64 x 128] += y[64 x 256] @ out_w^T ---
    int wave = tid >> 6, lane = tid & 63;
    int lr = lane & 15, lq = lane >> 4;
    int wm = wave * 16;
    f4 zf = {0.f, 0.f, 0.f, 0.f};
    f4 acc[8];
#pragma unroll
    for (int ni = 0; ni < 8; ++ni) acc[ni] = zf;
    const bf16_t* Bp = owb + (size_t)lr * DI + lq * 8;
#pragma unroll
    for (int kk = 0; kk < DI; kk += 32) {
        bf8 af = *(const bf8*)&yt[(wm + lr) * PADI + lq * 8 + kk];
        bf8 bq[8];
#pragma unroll
        for (int ni = 0; ni < 8; ++ni)
            bq[ni] = *(const bf8*)(Bp + (size_t)ni * 16 * DI + kk);
#pragma unroll
        for (int ni = 0; ni < 8; ++ni)
            acc[ni] = __builtin_amdgcn_mfma_f32_16x16x32_bf16(
                af, bq[ni], acc[ni], 0, 0, 0);
    }
    __syncthreads();   // yt reads done; epit may be overwritten
#pragma unroll
    for (int ni = 0; ni < 8; ++ni)
#pragma unroll
        for (int r = 0; r < 4; ++r)
            epit[(wm + lq * 4 + r) * 132 + ni * 16 + lr] = acc[ni][r];
    __syncthreads();
    for (int i = tid; i < 2048; i += 256) {
        int row = i >> 5, col = (i & 31) * 4;
        float4 v = *(const float4*)&epit[row * 132 + col];
        float4 old = *(const float4*)&h[(tokBase + row) * DM + col];
        old.x += v.x; old.y += v.y; old.z += v.z; old.w += v.w;
        *(float4*)&h[(tokBase + row) * DM + col] = old;
    }
}

// ---------------------------------------------------------------------------
__global__ __launch_bounds__(256) void k_final(float* __restrict__ h,
                                               const float* __restrict__ w,
                                               const float* __restrict__ bias,
                                               float* __restrict__ hg) {
    __shared__ float sbuf[DM];
    int t    = blockIdx.x * 16 + (threadIdx.x >> 4);
    int lane = threadIdx.x & 15;
    int b    = t >> 13;
    if (threadIdx.x < DM) sbuf[threadIdx.x] = 0.f;
    __syncthreads();
    float4* hp = (float4*)(h + (size_t)t * DM + lane * 8);
    float4 v0 = hp[0], v1 = hp[1];
    float s = v0.x + v0.y + v0.z + v0.w + v1.x + v1.y + v1.z + v1.w;
    float q = v0.x*v0.x + v0.y*v0.y + v0.z*v0.z + v0.w*v0.w +
              v1.x*v1.x + v1.y*v1.y + v1.z*v1.z + v1.w*v1.w;
#pragma unroll
    for (int off = 1; off < 16; off <<= 1) {
        s += __shfl_xor(s, off);
        q += __shfl_xor(q, off);
    }
    float mean = s * (1.f / DM);
    float var  = q * (1.f / DM) - mean * mean;
    float rstd = rsqrtf(var + 1e-5f);
    const float4* wp = (const float4*)(w + lane * 8);
    const float4* bp = (const float4*)(bias + lane * 8);
    float4 w0 = wp[0], w1 = wp[1], b0 = bp[0], b1 = bp[1];
    float4 o0, o1;
    o0.x = (v0.x - mean) * rstd * w0.x + b0.x;
    o0.y = (v0.y - mean) * rstd * w0.y + b0.y;
    o0.z = (v0.z - mean) * rstd * w0.z + b0.z;
    o0.w = (v0.w - mean) * rstd * w0.w + b0.w;
    o1.x = (v1.x - mean) * rstd * w1.x + b1.x;
    o1.y = (v1.y - mean) * rstd * w1.y + b1.y;
    o1.z = (v1.z - mean) * rstd * w1.z + b1.z;
    o1.w = (v1.w - mean) * rstd * w1.w + b1.w;
    hp[0] = o0; hp[1] = o1;
    int dbase = lane * 8;
    atomicAdd(&sbuf[dbase + 0], o0.x); atomicAdd(&sbuf[dbase + 1], o0.y);
    atomicAdd(&sbuf[dbase + 2], o0.z); atomicAdd(&sbuf[dbase + 3], o0.w);
    atomicAdd(&sbuf[dbase + 4], o1.x); atomicAdd(&sbuf[dbase + 5], o1.y);
    atomicAdd(&sbuf[dbase + 6], o1.z); atomicAdd(&sbuf[dbase + 7], o1.w);
    __syncthreads();
    if (threadIdx.x < DM)
        atomicAdd(&hg[b * DM + threadIdx.x], sbuf[threadIdx.x] * (1.f / Lz));
}

// ---------------------------------------------------------------------------
extern "C" void kernel_launch(void* const* d_in, const int* in_sizes, int n_in,
                              void* d_out, int out_size, void* d_ws, size_t ws_size,
                              hipStream_t stream) {
    const float* x       = (const float*)d_in[0];
    const float* proj_w  = (const float*)d_in[1];
    const float* proj_b  = (const float*)d_in[2];
    const float* ln_w    = (const float*)d_in[3];
    const float* ln_b    = (const float*)d_in[4];
    const float* in_w    = (const float*)d_in[5];
    const float* conv_w  = (const float*)d_in[6];
    const float* conv_b  = (const float*)d_in[7];
    const float* xproj_w = (const float*)d_in[8];
    const float* dt_w    = (const float*)d_in[9];
    const float* dt_b    = (const float*)d_in[10];
    const float* A_log   = (const float*)d_in[11];
    const float* Dp      = (const float*)d_in[12];
    const float* out_w   = (const float*)d_in[13];
    const float* lnout_w = (const float*)d_in[14];
    const float* lnout_b = (const float*)d_in[15];

    float* out = (float*)d_out;
    float* h   = out;                        // [BL][128] lives in d_out
    float* hg  = out + (size_t)BLz * DM;     // [B][128]

    // Workspace layout (u_pre slot now unused — kept for layout stability).
    char* ws = (char*)d_ws;
    bf16_t* zs    = (bf16_t*)(ws + 33554432ULL);      // 32 MiB
    bf16_t* ybase = (bf16_t*)(ws + 67108864ULL);      // 32 MiB
    float*  dtc   = (float*) (ws + 100663296ULL);     // 6 MiB  (BL*24*4)
    float*  Q     = (float*) (ws + 106954752ULL);     // 16 MiB
    float*  sdtb  = (float*) (ws + 123731968ULL);     // 1 MiB
    bf16_t* inwb  = (bf16_t*)(ws + 124780544ULL);     // 512 KiB
    bf16_t* owb   = (bf16_t*)(ws + 125304832ULL);     // 256 KiB
    bf16_t* xwb   = (bf16_t*)(ws + 125566976ULL);     // 128 KiB

    k_wconv<<<1024, 256, 0, stream>>>(in_w, out_w, xproj_w, inwb, owb, xwb, hg);
    k_inproj<<<BLz / 2, 256, 0, stream>>>(x, proj_w, proj_b, h);

    for (int i = 0; i < DEPTHN; ++i) {
        k_lnscan<<<BLz / CHT, 256, 0, stream>>>(
            h, ln_w + i * DM, ln_b + i * DM,
            inwb + (size_t)i * 512 * DM, xwb + (size_t)i * 64 * DI,
            conv_w + i * DI * 4, conv_b + i * DI,
            dt_w + i * DI * DTR, dt_b + i * DI, A_log + i * DI * DS,
            Dp + i * DI, zs, dtc, Q, sdtb, ybase);
        k_scan2<<<(Bz * DI * DS) / 128, 128, 0, stream>>>(
            Q, sdtb, A_log + i * DI * DS);
        k_corr_out<<<BLz / CHT, 256, 0, stream>>>(
            dtc, ybase, zs,
            dt_w + i * DI * DTR, dt_b + i * DI,
            A_log + i * DI * DS, Q,
            owb + (size_t)i * DM * DI, h);
    }

    k_final<<<BLz / 16, 256, 0, stream>>>(h, lnout_w, lnout_b, hg);
}

// Round 6
// 842.103 us; speedup vs baseline: 1.2263x; 1.0306x over previous
//
#include <hip/hip_runtime.h>
#include <hip/hip_bf16.h>
#include <math.h>

// Problem constants (MambaEncoder)
#define Bz     8
#define Lz     8192
#define DM     128      // d_model
#define DI     256      // d_inner
#define DS     16       // d_state
#define DTR    8        // dt_rank
#define NDBL   40       // DTR + 2*DS
#define DEPTHN 4
#define BLz    (Bz*Lz)  // 65536 tokens
#define CHT    64       // scan chunk length == M-tile
#define NCH    (Lz/CHT) // 128 chunks per sequence
#define PADI   264      // bf16 tile row stride
#define PADD   44       // f32 Db row stride

typedef unsigned short bf16_t;
typedef __attribute__((ext_vector_type(8))) __bf16 bf8;
typedef __attribute__((ext_vector_type(4))) float f4;
typedef __attribute__((ext_vector_type(8))) unsigned short us8;

__device__ __forceinline__ float bf2f(bf16_t u) {
    return __uint_as_float(((unsigned)u) << 16);
}
__device__ __forceinline__ bf16_t f2bf(float f) {
    unsigned u = __float_as_uint(f);
    u = u + 0x7FFFu + ((u >> 16) & 1u);   // round-to-nearest-even
    return (bf16_t)(u >> 16);
}
__device__ __forceinline__ float fast_rcp(float x) {
    return __builtin_amdgcn_rcpf(x);
}

// dA power tree: dA[s] = e1^(s+1), depth 4.
__device__ __forceinline__ void pow_tree(float e1, float dA[DS]) {
    float e2 = e1 * e1, e3 = e2 * e1, e4 = e2 * e2;
    float e8 = e4 * e4;
    dA[0] = e1;       dA[1] = e2;       dA[2] = e3;       dA[3] = e4;
    dA[4] = e4 * e1;  dA[5] = e4 * e2;  dA[6] = e4 * e3;  dA[7] = e8;
    dA[8] = e8 * e1;  dA[9] = e8 * e2;  dA[10] = e8 * e3; dA[11] = e8 * e4;
    dA[12] = e8 * dA[4]; dA[13] = e8 * dA[5]; dA[14] = e8 * dA[6];
    dA[15] = e8 * e8;
}

// ---------------------------------------------------------------------------
// Convert weights fp32 -> bf16 (xproj padded 40->64 rows) + zero hg.
// ---------------------------------------------------------------------------
__global__ __launch_bounds__(256) void k_wconv(const float* __restrict__ inw,
                                               const float* __restrict__ ow,
                                               const float* __restrict__ xw,
                                               bf16_t* __restrict__ inwb,
                                               bf16_t* __restrict__ owb,
                                               bf16_t* __restrict__ xwb,
                                               float* __restrict__ hg) {
    int i = blockIdx.x * 256 + threadIdx.x;
    if (i < Bz * DM) hg[i] = 0.f;
    if (i < DEPTHN * 512 * DM) inwb[i] = f2bf(inw[i]);
    if (i < DEPTHN * DM * DI)  owb[i]  = f2bf(ow[i]);
    if (i < DEPTHN * 64 * DI) {
        int layer = i >> 14, rk = i & 16383, r = rk >> 8, k = rk & 255;
        xwb[i] = (r < NDBL) ? f2bf(xw[((size_t)layer * NDBL + r) * DI + k]) : (bf16_t)0;
    }
}

// ---------------------------------------------------------------------------
// FUSED per-64-token chunk: [PROJ0: pointwise in-projection from x, written
// to h + fed to LN from registers — bit-identical to the standalone k_inproj
// chain] LayerNorm (64+3 halo rows) -> in-proj GEMM (u -> As LDS; halo via
// extra MFMA m-tile @row51) -> z silu direct to zs -> conv+SiLU -> xproj
// GEMM -> scan1.  LDS: As 33792 + Rb 18496 = 52288 B -> 3 blocks/CU.
// ---------------------------------------------------------------------------
template <bool PROJ0>
__global__ __launch_bounds__(256, 3) void k_lnscan(
        const float* __restrict__ xg,
        const float* __restrict__ pw, const float* __restrict__ pb,
        float* __restrict__ h,
        const float* __restrict__ lw, const float* __restrict__ lb,
        const bf16_t* __restrict__ inwb, const bf16_t* __restrict__ xwb,
        const float* __restrict__ cw, const float* __restrict__ cb,
        const float* __restrict__ dtw, const float* __restrict__ dtb,
        const float* __restrict__ Alog, const float* __restrict__ Dpv,
        bf16_t* __restrict__ zs, float* __restrict__ dtc,
        float* __restrict__ Q, float* __restrict__ sdtb,
        bf16_t* __restrict__ ybase) {
    __shared__ bf16_t As[CHT * PADI];   // 33792 B: u tile (conv'd in place)
    __shared__ char   Rb[18496];        // xs(67x136 bf16) -> Db(64x44 f32)
    bf16_t* xs = (bf16_t*)Rb;
    float*  Db = (float*)Rb;

    int tid = threadIdx.x;
    size_t tokBase = (size_t)blockIdx.x * CHT;
    int b  = (int)(tokBase >> 13);
    int p0 = (int)(tokBase & (Lz - 1));
    int c  = p0 >> 6;
    int d  = tid;

    // --- P0: LayerNorm 64 chunk rows + 3 halo rows (xs rows 64..66) ---
#pragma unroll
    for (int p = 0; p < 5; ++p) {
        int row = p * 16 + (tid >> 4);
        if (row >= 67) continue;                 // whole 16-lane groups skip
        int lane = tid & 15;
        if (row >= 64 && p0 == 0) {              // no halo at seq start: zero
            ushort4 z4 = {0, 0, 0, 0};
            *(ushort4*)&xs[row * 136 + lane * 8]     = z4;
            *(ushort4*)&xs[row * 136 + lane * 8 + 4] = z4;
            continue;
        }
        size_t tok = (row < 64) ? (tokBase + row) : (tokBase - 3 + (row - 64));
        float4 v0, v1;
        if (PROJ0) {
            // pointwise projection, bit-identical to k_inproj's chain
            int l = (int)(tok & (Lz - 1));
            float xv0 = xg[(size_t)(b * 3 + 0) * Lz + l];
            float xv1 = xg[(size_t)(b * 3 + 1) * Lz + l];
            float xv2 = xg[(size_t)(b * 3 + 2) * Lz + l];
            int dbase = lane * 8;
            float av[8];
#pragma unroll
            for (int e = 0; e < 8; ++e) {
                int dd = dbase + e;
                float acc = pb[dd];
                acc += xv0 * pw[dd * 3 + 0];
                acc += xv1 * pw[dd * 3 + 1];
                acc += xv2 * pw[dd * 3 + 2];
                av[e] = acc;
            }
            v0 = make_float4(av[0], av[1], av[2], av[3]);
            v1 = make_float4(av[4], av[5], av[6], av[7]);
            if (row < 64) {
                *(float4*)&h[tok * DM + dbase]     = v0;
                *(float4*)&h[tok * DM + dbase + 4] = v1;
            }
        } else {
            const float4* hp = (const float4*)(h + tok * DM + lane * 8);
            v0 = hp[0]; v1 = hp[1];
        }
        float s = v0.x + v0.y + v0.z + v0.w + v1.x + v1.y + v1.z + v1.w;
        float q = v0.x*v0.x + v0.y*v0.y + v0.z*v0.z + v0.w*v0.w +
                  v1.x*v1.x + v1.y*v1.y + v1.z*v1.z + v1.w*v1.w;
#pragma unroll
        for (int off = 1; off < 16; off <<= 1) {
            s += __shfl_xor(s, off);
            q += __shfl_xor(q, off);
        }
        float mean = s * (1.f / DM);
        float var  = q * (1.f / DM) - mean * mean;
        float rstd = rsqrtf(var + 1e-5f);
        const float4* wp = (const float4*)(lw + lane * 8);
        const float4* bp = (const float4*)(lb + lane * 8);
        float4 w0 = wp[0], w1 = wp[1], b0 = bp[0], b1 = bp[1];
        ushort4 o0, o1;
        o0.x = f2bf((v0.x - mean) * rstd * w0.x + b0.x);
        o0.y = f2bf((v0.y - mean) * rstd * w0.y + b0.y);
        o0.z = f2bf((v0.z - mean) * rstd * w0.z + b0.z);
        o0.w = f2bf((v0.w - mean) * rstd * w0.w + b0.w);
        o1.x = f2bf((v1.x - mean) * rstd * w1.x + b1.x);
        o1.y = f2bf((v1.y - mean) * rstd * w1.y + b1.y);
        o1.z = f2bf((v1.z - mean) * rstd * w1.z + b1.z);
        o1.w = f2bf((v1.w - mean) * rstd * w1.w + b1.w);
        *(ushort4*)&xs[row * 136 + lane * 8]     = o0;
        *(ushort4*)&xs[row * 136 + lane * 8 + 4] = o1;
    }
    __syncthreads();   // (barrier 1) xs ready

    int wave = tid >> 6, lane = tid & 63;
    int lr = lane & 15, lq = lane >> 4;
    f4 zf = {0.f, 0.f, 0.f, 0.f};

    // --- P1: u-GEMM (cols 0..255, wave n-slice 64) -> As directly;
    //     fused halo m-tile (A rows 51+lr -> C rows 51..66, keep 64..66) ---
    float uh3 = 0.f, uh2 = 0.f, uh1 = 0.f;
    {
        int wn = wave * 64;
        f4 accu[4][4];
        f4 accH[4];
#pragma unroll
        for (int mi = 0; mi < 4; ++mi)
#pragma unroll
            for (int ni = 0; ni < 4; ++ni) accu[mi][ni] = zf;
#pragma unroll
        for (int ni = 0; ni < 4; ++ni) accH[ni] = zf;
        const bf16_t* Bp = inwb + (size_t)(wn + lr) * DM + lq * 8;
#pragma unroll
        for (int kk = 0; kk < DM; kk += 32) {
            bf8 af[4], afh, bq[4];
#pragma unroll
            for (int mi = 0; mi < 4; ++mi)
                af[mi] = *(const bf8*)&xs[(mi * 16 + lr) * 136 + lq * 8 + kk];
            afh = *(const bf8*)&xs[(51 + lr) * 136 + lq * 8 + kk];
#pragma unroll
            for (int ni = 0; ni < 4; ++ni)
                bq[ni] = *(const bf8*)(Bp + (size_t)ni * 16 * DM + kk);
#pragma unroll
            for (int mi = 0; mi < 4; ++mi)
#pragma unroll
                for (int ni = 0; ni < 4; ++ni)
                    accu[mi][ni] = __builtin_amdgcn_mfma_f32_16x16x32_bf16(
                        af[mi], bq[ni], accu[mi][ni], 0, 0, 0);
#pragma unroll
            for (int ni = 0; ni < 4; ++ni)
                accH[ni] = __builtin_amdgcn_mfma_f32_16x16x32_bf16(
                    afh, bq[ni], accH[ni], 0, 0, 0);
        }
#pragma unroll
        for (int mi = 0; mi < 4; ++mi)
#pragma unroll
            for (int ni = 0; ni < 4; ++ni)
#pragma unroll
                for (int r = 0; r < 4; ++r)
                    As[(mi * 16 + lq * 4 + r) * PADI + wn + ni * 16 + lr] =
                        f2bf(accu[mi][ni][r]);

        // halo rows 64..66 = (lq=3, r=1..3), lanes 48+lr hold col wn+ni*16+lr.
        if (p0 != 0) {
            int src   = 48 + (d & 15);
            int nisel = (d >> 4) & 3;
            float hv[3];
#pragma unroll
            for (int j = 0; j < 3; ++j) {
                float v0 = __shfl(bf2f(f2bf(accH[0][j + 1])), src);
                float v1 = __shfl(bf2f(f2bf(accH[1][j + 1])), src);
                float v2 = __shfl(bf2f(f2bf(accH[2][j + 1])), src);
                float v3 = __shfl(bf2f(f2bf(accH[3][j + 1])), src);
                hv[j] = (nisel == 0) ? v0 : (nisel == 1) ? v1
                      : (nisel == 2) ? v2 : v3;
            }
            uh3 = hv[0]; uh2 = hv[1]; uh1 = hv[2];
        }
    }

    // --- P2: z-GEMM (cols 256..511) -> silu -> DIRECT zs stores ---
    {
        int wnz = 256 + wave * 64;
        f4 accz[4][4];
#pragma unroll
        for (int mi = 0; mi < 4; ++mi)
#pragma unroll
            for (int ni = 0; ni < 4; ++ni) accz[mi][ni] = zf;
        const bf16_t* Bp = inwb + (size_t)(wnz + lr) * DM + lq * 8;
#pragma unroll
        for (int kk = 0; kk < DM; kk += 32) {
            bf8 af[4], bq[4];
#pragma unroll
            for (int mi = 0; mi < 4; ++mi)
                af[mi] = *(const bf8*)&xs[(mi * 16 + lr) * 136 + lq * 8 + kk];
#pragma unroll
            for (int ni = 0; ni < 4; ++ni)
                bq[ni] = *(const bf8*)(Bp + (size_t)ni * 16 * DM + kk);
#pragma unroll
            for (int mi = 0; mi < 4; ++mi)
#pragma unroll
                for (int ni = 0; ni < 4; ++ni)
                    accz[mi][ni] = __builtin_amdgcn_mfma_f32_16x16x32_bf16(
                        af[mi], bq[ni], accz[mi][ni], 0, 0, 0);
        }
        // direct scalar stores (same values/addresses as staged path)
#pragma unroll
        for (int mi = 0; mi < 4; ++mi)
#pragma unroll
            for (int ni = 0; ni < 4; ++ni)
#pragma unroll
                for (int r = 0; r < 4; ++r) {
                    float v = accz[mi][ni][r];
                    float sil = v * fast_rcp(1.f + __expf(-v));
                    zs[(tokBase + mi * 16 + lq * 4 + r) * DI
                       + wave * 64 + ni * 16 + lr] = f2bf(sil);
                }
    }

    // --- conv(k=4)+SiLU in place: column d was written by THIS wave in P1
    //     (wave w owns As cols [64w,64w+64)); same-wave LDS RAW is ordered,
    //     so no barrier needed before conv. ---
    {
        float cw0 = cw[d*4+0], cw1 = cw[d*4+1], cw2 = cw[d*4+2], cw3 = cw[d*4+3];
        float cbb = cb[d];
        float x3 = uh3, x2 = uh2, x1 = uh1;
#pragma unroll 8
        for (int t = 0; t < CHT; ++t) {
            float x0 = bf2f(As[t * PADI + d]);
            float conv = cbb + cw0*x3 + cw1*x2 + cw2*x1 + cw3*x0;
            float sil = conv * fast_rcp(1.f + __expf(-conv));
            As[t * PADI + d] = f2bf(sil);
            x3 = x2; x2 = x1; x1 = x0;
        }
    }
    __syncthreads();   // (barrier 2) As sil complete all waves; xs dead

    // --- xproj GEMM: Db[64 x 40] = u @ xw^T (overwrites xs region) ---
    {
        int wm = wave * 16;
        f4 acc[4];
#pragma unroll
        for (int ni = 0; ni < 4; ++ni) acc[ni] = zf;
        const bf16_t* Bp = xwb + (size_t)lr * DI + lq * 8;
#pragma unroll
        for (int kk = 0; kk < DI; kk += 32) {
            bf8 af = *(const bf8*)&As[(wm + lr) * PADI + lq * 8 + kk];
            bf8 bq[4];
#pragma unroll
            for (int ni = 0; ni < 4; ++ni)
                bq[ni] = *(const bf8*)(Bp + (size_t)ni * 16 * DI + kk);
#pragma unroll
            for (int ni = 0; ni < 4; ++ni)
                acc[ni] = __builtin_amdgcn_mfma_f32_16x16x32_bf16(
                    af, bq[ni], acc[ni], 0, 0, 0);
        }
#pragma unroll
        for (int ni = 0; ni < 4; ++ni)
#pragma unroll
            for (int r = 0; r < 4; ++r) {
                int col = ni * 16 + lr;
                if (col < NDBL)
                    Db[(wm + lq * 4 + r) * PADD + col] = acc[ni][r];
            }
    }
    __syncthreads();   // (barrier 3) Db ready
    // dtc (dt cols 0..7 + C cols 24..39 -> 24 cols) to global
    for (int i = tid; i < CHT * 24; i += 256) {
        int row = i / 24, cc = i - row * 24;
        dtc[(tokBase + row) * 24 + cc] = Db[row * PADD + (cc < 8 ? cc : cc + 16)];
    }

    // --- scan1 + local y (round-0 body, bit-identical) ---
    {
        float w[DTR];
#pragma unroll
        for (int r = 0; r < DTR; ++r) w[r] = dtw[d * DTR + r];
        float bb = dtb[d];
        float dp = Dpv[d];
        float a[DS], q[DS];
        const float4* ap = (const float4*)(Alog + d * DS);
#pragma unroll
        for (int s4 = 0; s4 < 4; ++s4) {
            float4 av = ap[s4];
            a[s4*4+0] = -__expf(av.x); a[s4*4+1] = -__expf(av.y);
            a[s4*4+2] = -__expf(av.z); a[s4*4+3] = -__expf(av.w);
        }
#pragma unroll
        for (int s = 0; s < DS; ++s) q[s] = 0.f;
        float a0 = a[0];
        bool fast = true;
#pragma unroll
        for (int s = 1; s < DS; ++s) {
            float ref = a0 * (float)(s + 1);
            fast = fast && (fabsf(a[s] - ref) <= 1e-5f * fabsf(ref) + 1e-7f);
        }
        float sdt = 0.f;
        bf16_t* yp = ybase + tokBase * DI + d;
        if (fast) {
#pragma unroll 4
            for (int t = 0; t < CHT; ++t) {
                float4 r0 = *(const float4*)&Db[t * PADD + 0];
                float4 r1 = *(const float4*)&Db[t * PADD + 4];
                float xv = bb + r0.x*w[0] + r0.y*w[1] + r0.z*w[2] + r0.w*w[3]
                              + r1.x*w[4] + r1.y*w[5] + r1.z*w[6] + r1.w*w[7];
                float dtv = (xv > 20.f) ? xv : __logf(1.f + __expf(xv));
                sdt += dtv;
                float uv = bf2f(As[t * PADI + d]);
                float dtu = dtv * uv;
                float e1 = __expf(dtv * a0);
                float dA[DS];
                pow_tree(e1, dA);
                float bv[DS], cv[DS];
                *(float4*)&bv[0]  = *(const float4*)&Db[t * PADD + 8];
                *(float4*)&bv[4]  = *(const float4*)&Db[t * PADD + 12];
                *(float4*)&bv[8]  = *(const float4*)&Db[t * PADD + 16];
                *(float4*)&bv[12] = *(const float4*)&Db[t * PADD + 20];
                *(float4*)&cv[0]  = *(const float4*)&Db[t * PADD + 24];
                *(float4*)&cv[4]  = *(const float4*)&Db[t * PADD + 28];
                *(float4*)&cv[8]  = *(const float4*)&Db[t * PADD + 32];
                *(float4*)&cv[12] = *(const float4*)&Db[t * PADD + 36];
                float y0 = 0.f, y1 = 0.f, y2 = 0.f, y3 = 0.f;
#pragma unroll
                for (int s = 0; s < DS; s += 4) {
                    q[s]   = q[s]   * dA[s]   + dtu * bv[s];
                    q[s+1] = q[s+1] * dA[s+1] + dtu * bv[s+1];
                    q[s+2] = q[s+2] * dA[s+2] + dtu * bv[s+2];
                    q[s+3] = q[s+3] * dA[s+3] + dtu * bv[s+3];
                    y0 += q[s]   * cv[s];
                    y1 += q[s+1] * cv[s+1];
                    y2 += q[s+2] * cv[s+2];
                    y3 += q[s+3] * cv[s+3];
                }
                float y = (y0 + y1) + (y2 + y3);
                yp[(size_t)t * DI] = f2bf(y + uv * dp);
            }
        } else {
            for (int t = 0; t < CHT; ++t) {
                float4 r0 = *(const float4*)&Db[t * PADD + 0];
                float4 r1 = *(const float4*)&Db[t * PADD + 4];
                float xv = bb + r0.x*w[0] + r0.y*w[1] + r0.z*w[2] + r0.w*w[3]
                              + r1.x*w[4] + r1.y*w[5] + r1.z*w[6] + r1.w*w[7];
                float dtv = (xv > 20.f) ? xv : __logf(1.f + __expf(xv));
                sdt += dtv;
                float uv = bf2f(As[t * PADI + d]);
                float dtu = dtv * uv;
                float bv[DS], cv[DS];
                *(float4*)&bv[0]  = *(const float4*)&Db[t * PADD + 8];
                *(float4*)&bv[4]  = *(const float4*)&Db[t * PADD + 12];
                *(float4*)&bv[8]  = *(const float4*)&Db[t * PADD + 16];
                *(float4*)&bv[12] = *(const float4*)&Db[t * PADD + 20];
                *(float4*)&cv[0]  = *(const float4*)&Db[t * PADD + 24];
                *(float4*)&cv[4]  = *(const float4*)&Db[t * PADD + 28];
                *(float4*)&cv[8]  = *(const float4*)&Db[t * PADD + 32];
                *(float4*)&cv[12] = *(const float4*)&Db[t * PADD + 36];
                float y = 0.f;
#pragma unroll
                for (int s = 0; s < DS; ++s) {
                    float dA = __expf(dtv * a[s]);
                    q[s] = q[s] * dA + dtu * bv[s];
                    y += q[s] * cv[s];
                }
                yp[(size_t)t * DI] = f2bf(y + uv * dp);
            }
        }
        size_t o = ((size_t)(b * NCH + c) * DI + d) * DS;
#pragma unroll
        for (int s = 0; s < DS; s += 4)
            *(float4*)&Q[o + s] = make_float4(q[s], q[s+1], q[s+2], q[s+3]);
        sdtb[(size_t)(b * NCH + c) * DI + d] = sdt;
    }
}

// ---------------------------------------------------------------------------
// Phase 2: decay from sdt (exact: prod exp(dtv*a) == exp(a*sum dtv)).
// Q[c] overwritten in place with chunk entry state. Double-buffered 16-deep
// prefetch.
// ---------------------------------------------------------------------------
__global__ __launch_bounds__(128) void k_scan2(float* __restrict__ Q,
                                               const float* __restrict__ sdtb,
                                               const float* __restrict__ Alog) {
    int gid = blockIdx.x * 128 + threadIdx.x;   // Bz*DI*DS threads
    int b = gid >> 12, r = gid & 4095;          // r = d*16 + s
    int d = r >> 4, s = r & 15;
    float a = -__expf(Alog[d * DS + s]);
    const size_t stride = (size_t)DI * DS;
    size_t base = (size_t)b * NCH * stride + r;
    const float* sp = sdtb + (size_t)b * NCH * DI + d;
    float hh = 0.f;
    float qq[16], sv[16];
#pragma unroll
    for (int j = 0; j < 16; ++j) {
        qq[j] = Q[base + (size_t)j * stride];
        sv[j] = sp[(size_t)j * DI];
    }
    for (int g = 0; g < NCH / 16; ++g) {
        float qn[16], sn[16];
        if (g + 1 < NCH / 16) {
#pragma unroll
            for (int j = 0; j < 16; ++j) {
                qn[j] = Q[base + (size_t)((g + 1) * 16 + j) * stride];
                sn[j] = sp[(size_t)((g + 1) * 16 + j) * DI];
            }
        }
        float ee[16];
#pragma unroll
        for (int j = 0; j < 16; ++j)
            ee[j] = __expf(a * sv[j]);
#pragma unroll
        for (int j = 0; j < 16; ++j) {
            size_t o = base + (size_t)(g * 16 + j) * stride;
            Q[o] = hh;
            hh = ee[j] * hh + qq[j];
        }
        if (g + 1 < NCH / 16) {
#pragma unroll
            for (int j = 0; j < 16; ++j) { qq[j] = qn[j]; sv[j] = sn[j]; }
        }
    }
}

// ---------------------------------------------------------------------------
// FUSED: correction + gate -> y tile -> out-GEMM h += y @ out_w^T.
// LAST: final LayerNorm + hg mean fused into the epilogue (block holds the
// full 64x128 accumulated h tile; LN replicates k_final's per-row 16-lane
// computation exactly -> h bit-identical; hg atomic grouping changes only).
// ---------------------------------------------------------------------------
template <bool LAST>
__global__ __launch_bounds__(256, 4) void k_corr_out(
        const float* __restrict__ dtc, const bf16_t* __restrict__ ybase,
        const bf16_t* __restrict__ zs,
        const float* __restrict__ dtw, const float* __restrict__ dtb,
        const float* __restrict__ Alog, const float* __restrict__ H0,
        const bf16_t* __restrict__ owb, float* __restrict__ h,
        const float* __restrict__ lnw, const float* __restrict__ lnb,
        float* __restrict__ hg) {
    __shared__ float epit[CHT * 132];  // 33792 B; aliased as bf16 y tile
    __shared__ float Dt8[CHT * 8];     // 2048 B
    __shared__ float Cs[CHT * DS];     // 4096 B
    __shared__ float sbuf[DM];         // 512 B (LAST only)
    bf16_t* yt = (bf16_t*)epit;

    int tid = threadIdx.x;
    size_t tokBase = (size_t)blockIdx.x * CHT;
    int b  = (int)(tokBase >> 13);
    int p0 = (int)(tokBase & (Lz - 1));
    int c  = p0 >> 6;

    for (int i = tid; i < CHT * 24; i += 256) {
        float v = dtc[tokBase * 24 + i];
        int t = i / 24, col = i - t * 24;
        if (col < 8) Dt8[t * 8 + col] = v;
        else         Cs[t * DS + (col - 8)] = v;
    }
    __syncthreads();

    // --- correction + gating (thread = d) ---
    {
        int d = tid;
        float w[DTR];
#pragma unroll
        for (int r = 0; r < DTR; ++r) w[r] = dtw[d * DTR + r];
        float bb = dtb[d];
        float a[DS], gh[DS];
        const float4* ap = (const float4*)(Alog + d * DS);
#pragma unroll
        for (int s4 = 0; s4 < 4; ++s4) {
            float4 av = ap[s4];
            a[s4*4+0] = -__expf(av.x); a[s4*4+1] = -__expf(av.y);
            a[s4*4+2] = -__expf(av.z); a[s4*4+3] = -__expf(av.w);
        }
        size_t ho = ((size_t)(b * NCH + c) * DI + d) * DS;
#pragma unroll
        for (int s = 0; s < DS; s += 4) {
            float4 hv = *(const float4*)&H0[ho + s];
            gh[s] = hv.x; gh[s+1] = hv.y; gh[s+2] = hv.z; gh[s+3] = hv.w;
        }
        float a0 = a[0];
        bool fast = true;
#pragma unroll
        for (int s = 1; s < DS; ++s) {
            float ref = a0 * (float)(s + 1);
            fast = fast && (fabsf(a[s] - ref) <= 1e-5f * fabsf(ref) + 1e-7f);
        }
        const bf16_t* yp = ybase + tokBase * DI + d;
        const bf16_t* zp = zs + tokBase * DI + d;
        float cdt = 0.f;
        float yc[4], zc[4];
#pragma unroll
        for (int j = 0; j < 4; ++j) {
            yc[j] = bf2f(yp[(size_t)j * DI]);
            zc[j] = bf2f(zp[(size_t)j * DI]);
        }
        for (int g = 0; g < CHT / 4; ++g) {
            float yn[4] = {0,0,0,0}, zn[4] = {0,0,0,0};
            if (g + 1 < CHT / 4) {
#pragma unroll
                for (int j = 0; j < 4; ++j) {
                    yn[j] = bf2f(yp[(size_t)((g + 1) * 4 + j) * DI]);
                    zn[j] = bf2f(zp[(size_t)((g + 1) * 4 + j) * DI]);
                }
            }
#pragma unroll
            for (int j = 0; j < 4; ++j) {
                int t = g * 4 + j;
                float4 r0 = *(const float4*)&Dt8[t * 8];
                float4 r1 = *(const float4*)&Dt8[t * 8 + 4];
                float xv = bb + r0.x*w[0] + r0.y*w[1] + r0.z*w[2] + r0.w*w[3]
                              + r1.x*w[4] + r1.y*w[5] + r1.z*w[6] + r1.w*w[7];
                float dtv = (xv > 20.f) ? xv : __logf(1.f + __expf(xv));
                cdt += dtv;
                float cv[DS];
                *(float4*)&cv[0]  = *(const float4*)&Cs[t * DS + 0];
                *(float4*)&cv[4]  = *(const float4*)&Cs[t * DS + 4];
                *(float4*)&cv[8]  = *(const float4*)&Cs[t * DS + 8];
                *(float4*)&cv[12] = *(const float4*)&Cs[t * DS + 12];
                float corr0 = 0.f, corr1 = 0.f, corr2 = 0.f, corr3 = 0.f;
                if (fast) {
                    float e1 = __expf(a0 * cdt);
                    float dA[DS];
                    pow_tree(e1, dA);
#pragma unroll
                    for (int s = 0; s < DS; s += 4) {
                        corr0 += cv[s]   * (gh[s]   * dA[s]);
                        corr1 += cv[s+1] * (gh[s+1] * dA[s+1]);
                        corr2 += cv[s+2] * (gh[s+2] * dA[s+2]);
                        corr3 += cv[s+3] * (gh[s+3] * dA[s+3]);
                    }
                } else {
#pragma unroll
                    for (int s = 0; s < DS; ++s)
                        corr0 += cv[s] * (gh[s] * __expf(a[s] * cdt));
                }
                float y = yc[j] + ((corr0 + corr1) + (corr2 + corr3));
                yt[t * PADI + d] = f2bf(y * zc[j]);
            }
#pragma unroll
            for (int j = 0; j < 4; ++j) { yc[j] = yn[j]; zc[j] = zn[j]; }
        }
    }
    __syncthreads();

    // --- out-GEMM: h[64 x 128] += y[64 x 256] @ out_w^T ---
    int wave = tid >> 6, lane = tid & 63;
    int lr = lane & 15, lq = lane >> 4;
    int wm = wave * 16;
    f4 zf = {0.f, 0.f, 0.f, 0.f};
    f4 acc[8];
#pragma unroll
    for (int ni = 0; ni < 8; ++ni) acc[ni] = zf;
    const bf16_t* Bp = owb + (size_t)lr * DI + lq * 8;
#pragma unroll
    for (int kk = 0; kk < DI; kk += 32) {
        bf8 af = *(const bf8*)&yt[(wm + lr) * PADI + lq * 8 + kk];
        bf8 bq[8];
#pragma unroll
        for (int ni = 0; ni < 8; ++ni)
            bq[ni] = *(const bf8*)(Bp + (size_t)ni * 16 * DI + kk);
#pragma unroll
        for (int ni = 0; ni < 8; ++ni)
            acc[ni] = __builtin_amdgcn_mfma_f32_16x16x32_bf16(
                af, bq[ni], acc[ni], 0, 0, 0);
    }
    __syncthreads();   // yt reads done; epit may be overwritten
#pragma unroll
    for (int ni = 0; ni < 8; ++ni)
#pragma unroll
        for (int r = 0; r < 4; ++r)
            epit[(wm + lq * 4 + r) * 132 + ni * 16 + lr] = acc[ni][r];
    if (LAST) {
        if (tid < DM) sbuf[tid] = 0.f;
    }
    __syncthreads();
    if (!LAST) {
        for (int i = tid; i < 2048; i += 256) {
            int row = i >> 5, col = (i & 31) * 4;
            float4 v = *(const float4*)&epit[row * 132 + col];
            float4 old = *(const float4*)&h[(tokBase + row) * DM + col];
            old.x += v.x; old.y += v.y; old.z += v.z; old.w += v.w;
            *(float4*)&h[(tokBase + row) * DM + col] = old;
        }
    } else {
        // fused final LayerNorm + hg mean (k_final body, 4 passes of 16 rows)
#pragma unroll
        for (int p = 0; p < 4; ++p) {
            int row  = p * 16 + (tid >> 4);
            int lane16 = tid & 15;
            const float* ep = &epit[row * 132 + lane16 * 8];
            float4 e0 = *(const float4*)ep, e1 = *(const float4*)(ep + 4);
            float4* hp = (float4*)(h + (tokBase + row) * DM + lane16 * 8);
            float4 v0 = hp[0], v1 = hp[1];
            v0.x += e0.x; v0.y += e0.y; v0.z += e0.z; v0.w += e0.w;
            v1.x += e1.x; v1.y += e1.y; v1.z += e1.z; v1.w += e1.w;
            float s = v0.x + v0.y + v0.z + v0.w + v1.x + v1.y + v1.z + v1.w;
            float q = v0.x*v0.x + v0.y*v0.y + v0.z*v0.z + v0.w*v0.w +
                      v1.x*v1.x + v1.y*v1.y + v1.z*v1.z + v1.w*v1.w;
#pragma unroll
            for (int off = 1; off < 16; off <<= 1) {
                s += __shfl_xor(s, off);
                q += __shfl_xor(q, off);
            }
            float mean = s * (1.f / DM);
            float var  = q * (1.f / DM) - mean * mean;
            float rstd = rsqrtf(var + 1e-5f);
            const float4* wp2 = (const float4*)(lnw + lane16 * 8);
            const float4* bp2 = (const float4*)(lnb + lane16 * 8);
            float4 w0 = wp2[0], w1 = wp2[1], b0 = bp2[0], b1 = bp2[1];
            float4 o0, o1;
            o0.x = (v0.x - mean) * rstd * w0.x + b0.x;
            o0.y = (v0.y - mean) * rstd * w0.y + b0.y;
            o0.z = (v0.z - mean) * rstd * w0.z + b0.z;
            o0.w = (v0.w - mean) * rstd * w0.w + b0.w;
            o1.x = (v1.x - mean) * rstd * w1.x + b1.x;
            o1.y = (v1.y - mean) * rstd * w1.y + b1.y;
            o1.z = (v1.z - mean) * rstd * w1.z + b1.z;
            o1.w = (v1.w - mean) * rstd * w1.w + b1.w;
            hp[0] = o0; hp[1] = o1;
            int dbase = lane16 * 8;
            atomicAdd(&sbuf[dbase + 0], o0.x); atomicAdd(&sbuf[dbase + 1], o0.y);
            atomicAdd(&sbuf[dbase + 2], o0.z); atomicAdd(&sbuf[dbase + 3], o0.w);
            atomicAdd(&sbuf[dbase + 4], o1.x); atomicAdd(&sbuf[dbase + 5], o1.y);
            atomicAdd(&sbuf[dbase + 6], o1.z); atomicAdd(&sbuf[dbase + 7], o1.w);
        }
        __syncthreads();
        if (tid < DM)
            atomicAdd(&hg[b * DM + tid], sbuf[tid] * (1.f / Lz));
    }
}

// ---------------------------------------------------------------------------
extern "C" void kernel_launch(void* const* d_in, const int* in_sizes, int n_in,
                              void* d_out, int out_size, void* d_ws, size_t ws_size,
                              hipStream_t stream) {
    const float* x       = (const float*)d_in[0];
    const float* proj_w  = (const float*)d_in[1];
    const float* proj_b  = (const float*)d_in[2];
    const float* ln_w    = (const float*)d_in[3];
    const float* ln_b    = (const float*)d_in[4];
    const float* in_w    = (const float*)d_in[5];
    const float* conv_w  = (const float*)d_in[6];
    const float* conv_b  = (const float*)d_in[7];
    const float* xproj_w = (const float*)d_in[8];
    const float* dt_w    = (const float*)d_in[9];
    const float* dt_b    = (const float*)d_in[10];
    const float* A_log   = (const float*)d_in[11];
    const float* Dp      = (const float*)d_in[12];
    const float* out_w   = (const float*)d_in[13];
    const float* lnout_w = (const float*)d_in[14];
    const float* lnout_b = (const float*)d_in[15];

    float* out = (float*)d_out;
    float* h   = out;                        // [BL][128] lives in d_out
    float* hg  = out + (size_t)BLz * DM;     // [B][128]

    // Workspace layout (u_pre slot unused — kept for layout stability).
    char* ws = (char*)d_ws;
    bf16_t* zs    = (bf16_t*)(ws + 33554432ULL);      // 32 MiB
    bf16_t* ybase = (bf16_t*)(ws + 67108864ULL);      // 32 MiB
    float*  dtc   = (float*) (ws + 100663296ULL);     // 6 MiB  (BL*24*4)
    float*  Q     = (float*) (ws + 106954752ULL);     // 16 MiB
    float*  sdtb  = (float*) (ws + 123731968ULL);     // 1 MiB
    bf16_t* inwb  = (bf16_t*)(ws + 124780544ULL);     // 512 KiB
    bf16_t* owb   = (bf16_t*)(ws + 125304832ULL);     // 256 KiB
    bf16_t* xwb   = (bf16_t*)(ws + 125566976ULL);     // 128 KiB

    k_wconv<<<1024, 256, 0, stream>>>(in_w, out_w, xproj_w, inwb, owb, xwb, hg);

    for (int i = 0; i < DEPTHN; ++i) {
        if (i == 0)
            k_lnscan<true><<<BLz / CHT, 256, 0, stream>>>(
                x, proj_w, proj_b, h, ln_w + i * DM, ln_b + i * DM,
                inwb + (size_t)i * 512 * DM, xwb + (size_t)i * 64 * DI,
                conv_w + i * DI * 4, conv_b + i * DI,
                dt_w + i * DI * DTR, dt_b + i * DI, A_log + i * DI * DS,
                Dp + i * DI, zs, dtc, Q, sdtb, ybase);
        else
            k_lnscan<false><<<BLz / CHT, 256, 0, stream>>>(
                x, proj_w, proj_b, h, ln_w + i * DM, ln_b + i * DM,
                inwb + (size_t)i * 512 * DM, xwb + (size_t)i * 64 * DI,
                conv_w + i * DI * 4, conv_b + i * DI,
                dt_w + i * DI * DTR, dt_b + i * DI, A_log + i * DI * DS,
                Dp + i * DI, zs, dtc, Q, sdtb, ybase);
        k_scan2<<<(Bz * DI * DS) / 128, 128, 0, stream>>>(
            Q, sdtb, A_log + i * DI * DS);
        if (i == DEPTHN - 1)
            k_corr_out<true><<<BLz / CHT, 256, 0, stream>>>(
                dtc, ybase, zs,
                dt_w + i * DI * DTR, dt_b + i * DI,
                A_log + i * DI * DS, Q,
                owb + (size_t)i * DM * DI, h, lnout_w, lnout_b, hg);
        else
            k_corr_out<false><<<BLz / CHT, 256, 0, stream>>>(
                dtc, ybase, zs,
                dt_w + i * DI * DTR, dt_b + i * DI,
                A_log + i * DI * DS, Q,
                owb + (size_t)i * DM * DI, h, lnout_w, lnout_b, hg);
    }
}